// Round 13
// baseline (141.596 us; speedup 1.0000x reference)
//
#include <hip/hip_runtime.h>
#include <float.h>
#include <math.h>

typedef __attribute__((ext_vector_type(8))) short short8;
typedef __attribute__((ext_vector_type(4))) float f32x4;
typedef __attribute__((ext_vector_type(4))) unsigned short u16x4;
typedef unsigned short u16;
typedef unsigned int u32;

constexpr int B_ = 64, S_ = 512, N_ = 128, D_ = 768;

// ---------------------------------------------------------------------------
__device__ inline void split2h(float x, u16& h, u16& l) {
    _Float16 hh = (_Float16)x;
    _Float16 ll = (_Float16)(x - (float)hh);
    h = __builtin_bit_cast(u16, hh);
    l = __builtin_bit_cast(u16, ll);
}
__device__ inline u16 f2h(float x) {
    _Float16 hh = (_Float16)x;
    return __builtin_bit_cast(u16, hh);
}
__device__ inline float h2f(u16 h) {
    return (float)__builtin_bit_cast(_Float16, h);
}

__device__ inline void gload_lds16(const u16* g, u16* s) {
    __builtin_amdgcn_global_load_lds(
        (const __attribute__((address_space(1))) u32*)g,
        (__attribute__((address_space(3))) u32*)s, 16, 0, 0);
}

// Fragment-major layout for activation matrices [M][768]:
// u16 index of (row, col) = ((row>>4)*24 + (col>>5))*512
//                         + ((col>>3)&3)*128 + (row&15)*8 + (col&7)
__device__ inline int fragIdx(int row, int col) {
    return ((row >> 4) * 24 + (col >> 5)) * 512 + ((col >> 3) & 3) * 128
         + (row & 15) * 8 + (col & 7);
}

// ---------------------------------------------------------------------------
// tmps[b,n,:] = sum_{r=s+1..e} se[b,r,:]  -> split fp16 hi/lo, FRAG layout
__global__ __launch_bounds__(192)
void span_split_kernel(const float* __restrict__ se, const int* __restrict__ spans,
                       u16* __restrict__ th, u16* __restrict__ tl) {
    const int bn = blockIdx.x;
    const int b  = bn >> 7;
    const int s  = spans[bn * 2 + 0];
    const int e  = spans[bn * 2 + 1];
    const float* base = se + (size_t)b * S_ * D_;
    const int d4 = threadIdx.x;
    float4 acc = make_float4(0.f, 0.f, 0.f, 0.f);
    for (int r = s + 1; r <= e; ++r) {
        const float4 v = reinterpret_cast<const float4*>(base + (size_t)r * D_)[d4];
        acc.x += v.x; acc.y += v.y; acc.z += v.z; acc.w += v.w;
    }
    u16x4 hv, lv;
    u16 hh, ll;
    split2h(acc.x, hh, ll); hv[0] = hh; lv[0] = ll;
    split2h(acc.y, hh, ll); hv[1] = hh; lv[1] = ll;
    split2h(acc.z, hh, ll); hv[2] = hh; lv[2] = ll;
    split2h(acc.w, hh, ll); hv[3] = hh; lv[3] = ll;
    const int idx = fragIdx(bn, d4 * 4);
    *(u16x4*)(th + idx) = hv;
    *(u16x4*)(tl + idx) = lv;
}

// ---------------------------------------------------------------------------
// target_max: grid (64, 4); block covers 192 cols of batch b.
__global__ __launch_bounds__(192)
void target_max_kernel(const float* __restrict__ se, const int* __restrict__ tspan,
                       float* __restrict__ tmax) {
    const int b = blockIdx.x;
    const int c = blockIdx.y * 192 + threadIdx.x;
    const int s = tspan[b * 2 + 0];
    const int e = tspan[b * 2 + 1];
    const float* base = se + (size_t)b * S_ * D_ + c;
    float m = -FLT_MAX;
    for (int r = s; r < e; ++r) m = fmaxf(m, base[(size_t)r * D_]);
    tmax[(size_t)b * D_ + c] = m;
}

// ---------------------------------------------------------------------------
// adj = clamp(dg+dg1,1) -> fp16 (exact {0,1}) [b][n][k]; invden = 1/(rowsum+1e-7)
__global__ __launch_bounds__(128)
void adj_kernel(const float* __restrict__ dg, const float* __restrict__ dg1,
                u16* __restrict__ adj, float* __restrict__ invden) {
    const int row = blockIdx.x;
    const int t   = threadIdx.x;
    const size_t idx = (size_t)row * N_ + t;
    float a = dg[idx] + dg1[idx];
    a = (a >= 1.f) ? 1.f : a;
    adj[idx] = f2h(a);
    float w = a;
    #pragma unroll
    for (int off = 32; off; off >>= 1) w += __shfl_down(w, off, 64);
    __shared__ float ssum[2];
    if ((t & 63) == 0) ssum[t >> 6] = w;
    __syncthreads();
    if (t == 0) invden[row] = 1.f / (ssum[0] + ssum[1] + 1e-7f);
}

// ---------------------------------------------------------------------------
// Weights: W[k][n] (768x768) -> WT[n][k] single fp16. blockIdx.z = matrix.
__global__ __launch_bounds__(256)
void wsplit_kernel(const float* __restrict__ W0, const float* __restrict__ W1,
                   const float* __restrict__ W2, const float* __restrict__ W3,
                   u16* __restrict__ wth) {
    __shared__ float t[64][65];
    const int mi = blockIdx.z;
    const float* W = (mi == 0) ? W0 : (mi == 1) ? W1 : (mi == 2) ? W2 : W3;
    const int k0 = blockIdx.y * 64, n0 = blockIdx.x * 64;
    #pragma unroll 4
    for (int it = 0; it < 16; ++it) {
        const int lin = it * 256 + threadIdx.x;
        const int r = lin >> 6, c = lin & 63;
        t[r][c] = W[(size_t)(k0 + r) * D_ + n0 + c];
    }
    __syncthreads();
    u16* oh = wth + (size_t)mi * D_ * D_;
    #pragma unroll 4
    for (int it = 0; it < 16; ++it) {
        const int lin = it * 256 + threadIdx.x;
        const int r = lin >> 6, c = lin & 63;
        oh[(size_t)(n0 + r) * D_ + k0 + c] = f2h(t[c][r]);
    }
}

// ---------------------------------------------------------------------------
// Fused fp16 GEMM (H ~= Ah @ W). 128x96 tile, 4 waves (2x2, wave tile 64x48,
// mf=4 nf=3 -> 28 flop/LDS-byte), 512 blocks = 4 blocks/CU, 16 waves/CU.
// A staged through LDS once/block (tri-buf 3x8KB); B LDS dbl-buf 2x6KB.
// Per iter (after barrier): issue B(t+1) THEN A(t+2); steady wait vmcnt(2)
// leaves only the 2 newest (A(t+2)) outstanding => B(t), A(t) landed.
// MODE 0: store relu(H) split fp16 hi/lo, FRAG layout.
// MODE 1: out = relu((adj[b]@H)*invden + bias) + X_in (FRAG layout);
//   adj per-ks prefetched VGPR pairs; hwT (24 KB) overlays A region.
template<int MODE>
__global__ __launch_bounds__(256, 4)
void gemm_fused(const u16* __restrict__ Ah, const u16* __restrict__ Al,
                const u16* __restrict__ Bh,
                const u16* __restrict__ ADJ, const float* __restrict__ invden,
                const float* __restrict__ bias,
                u16* __restrict__ Oh, u16* __restrict__ Ol) {
    __shared__ u16 lds[18432];   // A tri-buf [0,12288) | B dbl-buf [12288,18432)
    const int tid  = threadIdx.x;
    const int lane = tid & 63, w = tid >> 6;     // 4 waves
    const int wr = w >> 1, wc = w & 1;           // 2 row x 2 col
    const int lr = lane & 15, lh = lane >> 4;

    int bid = blockIdx.x;
    bid = (bid & 7) * 64 + (bid >> 3);           // XCD swizzle (512 % 8 == 0)
    const int bnb = bid & 7, bmb = bid >> 3;
    const int bn = bnb * 96;

    // --- B staging: 6 groups (16 rows x 32k each); waves 0,1 take 2, waves 2,3 take 1
    const int qch = (lane & 3) ^ ((lane >> 3) & 3);
    const int bg0 = (w < 2) ? 2 * w : (w + 2);   // w0:0,1  w1:2,3  w2:4  w3:5
    const u16* gB0 = Bh + (size_t)(bn + bg0 * 16 + (lane >> 2)) * 768 + qch * 8;
    const u16* gB1 = gB0 + (size_t)16 * 768;     // second group (w<2 only)

    // --- A staging: wave w stages mblks 2w, 2w+1 (1KB contiguous per k-tile)
    const u16* gA0 = Ah + (size_t)(bmb * 8 + 2 * w) * 12288 + lane * 8;

    f32x4 acc[4][3];
    #pragma unroll
    for (int i = 0; i < 4; ++i)
        #pragma unroll
        for (int j = 0; j < 3; ++j)
            acc[i][j] = (f32x4){0.f, 0.f, 0.f, 0.f};

    // prologue: A(0) -> Abuf0, B(0) -> Bbuf0, A(1) -> Abuf1
    gload_lds16(gA0,          lds + (2 * w) * 512);
    gload_lds16(gA0 + 12288,  lds + (2 * w + 1) * 512);
    gload_lds16(gB0, lds + 12288 + bg0 * 512);
    if (w < 2) gload_lds16(gB1, lds + 12288 + (bg0 + 1) * 512);
    gload_lds16(gA0 + 512,         lds + 4096 + (2 * w) * 512);
    gload_lds16(gA0 + 12288 + 512, lds + 4096 + (2 * w + 1) * 512);

    const int pB = (lh ^ ((lr >> 1) & 3)) << 3;  // B frag phys chunk offset (u16)

// One K-step. C = compile-time phase (t_ % 6). Abuf = C%3, Bbuf = C%2.
#define GEMM_ITER(C)                                                          \
    {                                                                         \
        const int t_ = 6 * tt + (C);                                          \
        if (t_ <= 22) asm volatile("s_waitcnt vmcnt(2)" ::: "memory");        \
        else          asm volatile("s_waitcnt vmcnt(0)" ::: "memory");        \
        __builtin_amdgcn_s_barrier();                                         \
        __builtin_amdgcn_sched_barrier(0);                                    \
        if (t_ + 1 <= 23) {                                                   \
            u16* bb = lds + 12288 + (((C) + 1) & 1) * 3072;                   \
            gload_lds16(gB0 + (t_ + 1) * 32, bb + bg0 * 512);                 \
            if (w < 2) gload_lds16(gB1 + (t_ + 1) * 32, bb + (bg0 + 1) * 512);\
        }                                                                     \
        if (t_ + 2 <= 23) {                                                   \
            u16* ab = lds + (((C) + 2) % 3) * 4096;                           \
            gload_lds16(gA0 + (t_ + 2) * 512,         ab + (2 * w) * 512);    \
            gload_lds16(gA0 + 12288 + (t_ + 2) * 512, ab + (2 * w + 1) * 512);\
        }                                                                     \
        const u16* La = lds + ((C) % 3) * 4096;                               \
        const u16* Lb = lds + 12288 + ((C) & 1) * 3072;                       \
        short8 aF[4], bF[3];                                                  \
        _Pragma("unroll")                                                     \
        for (int mf = 0; mf < 4; ++mf)                                        \
            aF[mf] = *(const short8*)&La[(wr * 4 + mf) * 512 + lane * 8];     \
        _Pragma("unroll")                                                     \
        for (int f = 0; f < 3; ++f)                                           \
            bF[f] = *(const short8*)&Lb[(wc * 48 + f * 16 + lr) * 32 + pB];   \
        __builtin_amdgcn_s_setprio(1);                                        \
        _Pragma("unroll")                                                     \
        for (int mf = 0; mf < 4; ++mf)                                        \
            _Pragma("unroll")                                                 \
            for (int nf = 0; nf < 3; ++nf)                                    \
                acc[mf][nf] = __builtin_amdgcn_mfma_f32_16x16x32_f16(aF[mf], bF[nf], acc[mf][nf], 0, 0, 0); \
        __builtin_amdgcn_s_setprio(0);                                        \
    }

    for (int tt = 0; tt < 4; ++tt) {
        GEMM_ITER(0)
        GEMM_ITER(1)
        GEMM_ITER(2)
        GEMM_ITER(3)
        GEMM_ITER(4)
        GEMM_ITER(5)
    }
#undef GEMM_ITER

    if (MODE == 0) {
        #pragma unroll
        for (int mf = 0; mf < 4; ++mf) {
            const int mblk = bmb * 8 + wr * 4 + mf;
            #pragma unroll
            for (int r = 0; r < 4; ++r) {
                const int lane_r = lh * 4 + r;
                #pragma unroll
                for (int nf = 0; nf < 3; ++nf) {
                    const int c = bn + wc * 48 + nf * 16 + lr;
                    const int idx = (mblk * 24 + (c >> 5)) * 512
                                  + ((c >> 3) & 3) * 128 + lane_r * 8 + (c & 7);
                    const float v = fmaxf(acc[mf][nf][r], 0.f);
                    u16 h, l; split2h(v, h, l);
                    Oh[idx] = h; Ol[idx] = l;
                }
            }
        }
        return;
    }

    // ---------------- MODE 1: phase 2 (adjacency GEMM) ----------------------
    // drain: all waves done reading K-loop buffers before hwT overwrites A region
    __builtin_amdgcn_s_barrier();
    __builtin_amdgcn_sched_barrier(0);

    // write H^T (single fp16) into LDS [c 96][node 128], chunk-swizzled
    u16* hwT = lds;                              // 12288 u16 = A-tri region
    #pragma unroll
    for (int mf = 0; mf < 4; ++mf) {
        const int node0 = wr * 64 + mf * 16 + lh * 4;
        #pragma unroll
        for (int nf = 0; nf < 3; ++nf) {
            const int c = wc * 48 + nf * 16 + lr;
            u16x4 hv;
            #pragma unroll
            for (int r = 0; r < 4; ++r) hv[r] = f2h(acc[mf][nf][r]);
            *(u16x4*)&hwT[c * 128 + (((node0 >> 3) ^ (c & 7)) << 3) + (node0 & 7)] = hv;
        }
    }
    asm volatile("s_waitcnt lgkmcnt(0)" ::: "memory");
    __builtin_amdgcn_s_barrier();
    __builtin_amdgcn_sched_barrier(0);

    const u16* adjb = ADJ + (size_t)bmb * (N_ * N_);
    f32x4 acc2[4][3];
    #pragma unroll
    for (int i = 0; i < 4; ++i)
        #pragma unroll
        for (int j = 0; j < 3; ++j)
            acc2[i][j] = (f32x4){0.f, 0.f, 0.f, 0.f};

    // adj fragments: per-ks double-buffered in VGPRs (keeps pressure <=128)
    short8 adjA[4], adjB[4];
    #pragma unroll
    for (int mf = 0; mf < 4; ++mf)
        adjA[mf] = *(const short8*)(adjb +
            (size_t)(wr * 64 + mf * 16 + lr) * 128 + lh * 8);

    #pragma unroll
    for (int ks = 0; ks < 4; ++ks) {
        if (ks < 3) {
            #pragma unroll
            for (int mf = 0; mf < 4; ++mf) {
                short8* dst = (ks & 1) ? &adjA[mf] : &adjB[mf];
                *dst = *(const short8*)(adjb +
                    (size_t)(wr * 64 + mf * 16 + lr) * 128 + (ks + 1) * 32 + lh * 8);
            }
        }
        short8 bf[3];
        #pragma unroll
        for (int f = 0; f < 3; ++f) {
            const int c = wc * 48 + f * 16 + lr;
            bf[f] = *(const short8*)&hwT[c * 128 + (((ks * 4 + lh) ^ (c & 7)) << 3)];
        }
        #pragma unroll
        for (int mf = 0; mf < 4; ++mf) {
            const short8 af = (ks & 1) ? adjB[mf] : adjA[mf];
            #pragma unroll
            for (int nf = 0; nf < 3; ++nf)
                acc2[mf][nf] = __builtin_amdgcn_mfma_f32_16x16x32_f16(af, bf[nf], acc2[mf][nf], 0, 0, 0);
        }
    }

    // epilogue: out = relu(acc2*inv + bias) + X_in; split fp16; store FRAG
    #pragma unroll
    for (int mf = 0; mf < 4; ++mf) {
        const int mblk = bmb * 8 + wr * 4 + mf;
        #pragma unroll
        for (int r = 0; r < 4; ++r) {
            const int node = wr * 64 + mf * 16 + lh * 4 + r;
            const int lane_r = lh * 4 + r;
            const float inv = invden[bmb * N_ + node];
            #pragma unroll
            for (int nf = 0; nf < 3; ++nf) {
                const int c = bn + wc * 48 + nf * 16 + lr;
                const int idx = (mblk * 24 + (c >> 5)) * 512
                              + ((c >> 3) & 3) * 128 + lane_r * 8 + (c & 7);
                float v = fmaxf(acc2[mf][nf][r] * inv + bias[c], 0.f);
                v += h2f(Ah[idx]) + h2f(Al[idx]);   // residual = A-source hi+lo
                u16 h, l; split2h(v, h, l);
                Oh[idx] = h; Ol[idx] = l;
            }
        }
    }
}

// ---------------------------------------------------------------------------
// gcn_target: grid (64, 4); block covers 192 cols of batch b.
__global__ __launch_bounds__(192)
void gcn_target_kernel(const u16* __restrict__ Xh, const u16* __restrict__ Xl,
                       const int* __restrict__ gspan, float* __restrict__ gt) {
    const int b = blockIdx.x;
    const int c = blockIdx.y * 192 + threadIdx.x;
    const int s = gspan[b * 2 + 0];
    const int e = gspan[b * 2 + 1];
    float acc = 0.f;
    for (int n = s; n < e; ++n) {
        const int idx = fragIdx(b * N_ + n, c);
        acc += h2f(Xh[idx]) + h2f(Xl[idx]);
    }
    gt[(size_t)b * D_ + c] = acc;
}

// ---------------------------------------------------------------------------
__global__ __launch_bounds__(256)
void head_kernel(const float* __restrict__ tmax, const float* __restrict__ gt,
                 const float* __restrict__ fcW, const float* __restrict__ fcb,
                 float* __restrict__ out) {
    const int b = blockIdx.x;
    const int t = threadIdx.x;
    float p0 = 0.f, p1 = 0.f, p2 = 0.f;
    for (int i = t; i < 2 * D_; i += 256) {
        const float v = (i < D_) ? tmax[(size_t)b * D_ + i] : gt[(size_t)b * D_ + i - D_];
        p0 += v * fcW[i * 3 + 0];
        p1 += v * fcW[i * 3 + 1];
        p2 += v * fcW[i * 3 + 2];
    }
    #pragma unroll
    for (int off = 32; off; off >>= 1) {
        p0 += __shfl_down(p0, off, 64);
        p1 += __shfl_down(p1, off, 64);
        p2 += __shfl_down(p2, off, 64);
    }
    __shared__ float red[4][3];
    const int wv = t >> 6;
    if ((t & 63) == 0) { red[wv][0] = p0; red[wv][1] = p1; red[wv][2] = p2; }
    __syncthreads();
    if (t == 0) {
        #pragma unroll
        for (int o = 0; o < 3; ++o) {
            const float s = red[0][o] + red[1][o] + red[2][o] + red[3][o] + fcb[o];
            out[b * 3 + o] = tanhf(s);
        }
    }
}

// ---------------------------------------------------------------------------
extern "C" void kernel_launch(void* const* d_in, const int* in_sizes, int n_in,
                              void* d_out, int out_size, void* d_ws, size_t ws_size,
                              hipStream_t stream) {
    const float* se   = (const float*)d_in[0];
    const float* dg   = (const float*)d_in[1];
    const float* dg1  = (const float*)d_in[2];
    const float* Wp   = (const float*)d_in[3];
    const float* Wg[3] = {(const float*)d_in[4], (const float*)d_in[6], (const float*)d_in[8]};
    const float* bg[3] = {(const float*)d_in[5], (const float*)d_in[7], (const float*)d_in[9]};
    const float* fcW  = (const float*)d_in[10];
    const float* fcb  = (const float*)d_in[11];
    const int*   tspan  = (const int*)d_in[12];
    const int*   nspans = (const int*)d_in[13];
    const int*   gspan  = (const int*)d_in[14];
    float* out = (float*)d_out;

    // workspace layout (u16 units unless noted)
    u16* us   = (u16*)d_ws;
    u16* X0h  = us;                        // 8192*768 each (FRAG layout)
    u16* X0l  = X0h + 6291456;
    u16* X1h  = X0l + 6291456;
    u16* X1l  = X1h + 6291456;
    u16* TH   = X1l + 6291456;             // tmps hi/lo (FRAG layout)
    u16* TL   = TH  + 6291456;
    u16* WTh  = TL  + 6291456;             // 4*768*768 fp16 (single)
    u16* ADJ  = WTh + 2359296;             // 64*128*128 fp16
    float* INV = (float*)(ADJ + 1048576);  // 8192
    float* TMX = INV + 8192;               // 64*768
    float* GT  = TMX + 49152;              // 64*768

    // Stage A: ragged prep
    span_split_kernel<<<B_ * N_, 192, 0, stream>>>(se, nspans, TH, TL);
    target_max_kernel<<<dim3(B_, 4), 192, 0, stream>>>(se, tspan, TMX);
    adj_kernel<<<B_ * N_, 128, 0, stream>>>(dg, dg1, ADJ, INV);
    wsplit_kernel<<<dim3(12, 12, 4), 256, 0, stream>>>(Wp, Wg[0], Wg[1], Wg[2], WTh);

    // Stage B: X0 = relu(tmps @ W_proj)   (512 blocks: 64 row-panels x 8 col-96)
    gemm_fused<0><<<512, 256, 0, stream>>>(TH, TL, WTh,
                                           nullptr, nullptr, nullptr, X0h, X0l);

    // Stage C: 3 fused GCN layers (ping-pong X0 <-> X1)
    const u16* inh[3] = {X0h, X1h, X0h};
    const u16* inl[3] = {X0l, X1l, X0l};
    u16* outh[3] = {X1h, X0h, X1h};
    u16* outl[3] = {X1l, X0l, X1l};
    for (int l = 0; l < 3; ++l) {
        const size_t wo = (size_t)(l + 1) * D_ * D_;
        gemm_fused<1><<<512, 256, 0, stream>>>(inh[l], inl[l], WTh + wo,
                                               ADJ, INV, bg[l], outh[l], outl[l]);
    }

    // Stage D: ragged node-span sum + head (final X lives in X1)
    gcn_target_kernel<<<dim3(B_, 4), 192, 0, stream>>>(X1h, X1l, gspan, GT);
    head_kernel<<<B_, 256, 0, stream>>>(TMX, GT, fcW, fcb, out);
}

// Round 14
// 110.366 us; speedup vs baseline: 1.2830x; 1.2830x over previous
//
#include <hip/hip_runtime.h>
#include <float.h>
#include <math.h>

typedef __attribute__((ext_vector_type(8))) short short8;
typedef __attribute__((ext_vector_type(4))) float f32x4;
typedef __attribute__((ext_vector_type(4))) unsigned short u16x4;
typedef unsigned short u16;
typedef unsigned int u32;

constexpr int B_ = 64, S_ = 512, N_ = 128, D_ = 768;

// ---------------------------------------------------------------------------
__device__ inline u16 f2h(float x) {
    _Float16 hh = (_Float16)x;
    return __builtin_bit_cast(u16, hh);
}
__device__ inline float h2f(u16 h) {
    return (float)__builtin_bit_cast(_Float16, h);
}

__device__ inline void gload_lds16(const u16* g, u16* s) {
    __builtin_amdgcn_global_load_lds(
        (const __attribute__((address_space(1))) u32*)g,
        (__attribute__((address_space(3))) u32*)s, 16, 0, 0);
}

// Fragment-major layout for activation matrices [M][768]:
// u16 index of (row, col) = ((row>>4)*24 + (col>>5))*512
//                         + ((col>>3)&3)*128 + (row&15)*8 + (col&7)
__device__ inline int fragIdx(int row, int col) {
    return ((row >> 4) * 24 + (col >> 5)) * 512 + ((col >> 3) & 3) * 128
         + (row & 15) * 8 + (col & 7);
}

// ---------------------------------------------------------------------------
// tmps[b,n,:] = sum_{r=s+1..e} se[b,r,:]  -> single fp16, FRAG layout
__global__ __launch_bounds__(192)
void span_split_kernel(const float* __restrict__ se, const int* __restrict__ spans,
                       u16* __restrict__ th) {
    const int bn = blockIdx.x;
    const int b  = bn >> 7;
    const int s  = spans[bn * 2 + 0];
    const int e  = spans[bn * 2 + 1];
    const float* base = se + (size_t)b * S_ * D_;
    const int d4 = threadIdx.x;
    float4 acc = make_float4(0.f, 0.f, 0.f, 0.f);
    for (int r = s + 1; r <= e; ++r) {
        const float4 v = reinterpret_cast<const float4*>(base + (size_t)r * D_)[d4];
        acc.x += v.x; acc.y += v.y; acc.z += v.z; acc.w += v.w;
    }
    u16x4 hv;
    hv[0] = f2h(acc.x); hv[1] = f2h(acc.y);
    hv[2] = f2h(acc.z); hv[3] = f2h(acc.w);
    *(u16x4*)(th + fragIdx(bn, d4 * 4)) = hv;
}

// ---------------------------------------------------------------------------
// target_max: grid (64, 4); block covers 192 cols of batch b.
__global__ __launch_bounds__(192)
void target_max_kernel(const float* __restrict__ se, const int* __restrict__ tspan,
                       float* __restrict__ tmax) {
    const int b = blockIdx.x;
    const int c = blockIdx.y * 192 + threadIdx.x;
    const int s = tspan[b * 2 + 0];
    const int e = tspan[b * 2 + 1];
    const float* base = se + (size_t)b * S_ * D_ + c;
    float m = -FLT_MAX;
    for (int r = s; r < e; ++r) m = fmaxf(m, base[(size_t)r * D_]);
    tmax[(size_t)b * D_ + c] = m;
}

// ---------------------------------------------------------------------------
// adj = clamp(dg+dg1,1) -> fp16 (exact {0,1}) [b][n][k]; invden = 1/(rowsum+1e-7)
__global__ __launch_bounds__(128)
void adj_kernel(const float* __restrict__ dg, const float* __restrict__ dg1,
                u16* __restrict__ adj, float* __restrict__ invden) {
    const int row = blockIdx.x;
    const int t   = threadIdx.x;
    const size_t idx = (size_t)row * N_ + t;
    float a = dg[idx] + dg1[idx];
    a = (a >= 1.f) ? 1.f : a;
    adj[idx] = f2h(a);
    float w = a;
    #pragma unroll
    for (int off = 32; off; off >>= 1) w += __shfl_down(w, off, 64);
    __shared__ float ssum[2];
    if ((t & 63) == 0) ssum[t >> 6] = w;
    __syncthreads();
    if (t == 0) invden[row] = 1.f / (ssum[0] + ssum[1] + 1e-7f);
}

// ---------------------------------------------------------------------------
// Weights: W[k][n] (768x768) -> WT[n][k] single fp16. blockIdx.z = matrix.
__global__ __launch_bounds__(256)
void wsplit_kernel(const float* __restrict__ W0, const float* __restrict__ W1,
                   const float* __restrict__ W2, const float* __restrict__ W3,
                   u16* __restrict__ wth) {
    __shared__ float t[64][65];
    const int mi = blockIdx.z;
    const float* W = (mi == 0) ? W0 : (mi == 1) ? W1 : (mi == 2) ? W2 : W3;
    const int k0 = blockIdx.y * 64, n0 = blockIdx.x * 64;
    #pragma unroll 4
    for (int it = 0; it < 16; ++it) {
        const int lin = it * 256 + threadIdx.x;
        const int r = lin >> 6, c = lin & 63;
        t[r][c] = W[(size_t)(k0 + r) * D_ + n0 + c];
    }
    __syncthreads();
    u16* oh = wth + (size_t)mi * D_ * D_;
    #pragma unroll 4
    for (int it = 0; it < 16; ++it) {
        const int lin = it * 256 + threadIdx.x;
        const int r = lin >> 6, c = lin & 63;
        oh[(size_t)(n0 + r) * D_ + k0 + c] = f2h(t[c][r]);
    }
}

// ---------------------------------------------------------------------------
// Fused fp16 GEMM (H ~= A @ W, all single fp16 storage).
// 128x96 tile, 8 waves (4x2), 512 blocks (2/CU, 16 waves/CU).
// A staged through LDS once/block: FRAG-major global makes each mblk K-slice
// a contiguous 1KB -> one global_load_lds per wave per iter. A tri-buf 3x8KB,
// B tri-buf 3x6KB. Single barrier per K-step; counted vmcnt (steady 2/1).
// MODE 0: store relu(H) single fp16, FRAG layout.
// MODE 1: out = relu((adj[b]@H)*invden + bias) + X_in (FRAG layout);
//   adj in VGPRs post-loop; hwT (24 KB) reuses the A region after a drain.
template<int MODE>
__global__ __launch_bounds__(512, 4)
void gemm_fused(const u16* __restrict__ Ah,
                const u16* __restrict__ Bh,
                const u16* __restrict__ ADJ, const float* __restrict__ invden,
                const float* __restrict__ bias,
                u16* __restrict__ Oh) {
    __shared__ u16 lds[21504];   // A tri-buf [0,12288) | B tri-buf [12288,21504)
    const int tid  = threadIdx.x;
    const int lane = tid & 63, w = tid >> 6;     // 8 waves
    const int wr = w >> 1, wc = w & 1;           // 4 row x 2 col
    const int lr = lane & 15, lh = lane >> 4;

    int bid = blockIdx.x;
    bid = (bid & 7) * 64 + (bid >> 3);           // XCD swizzle (512 % 8 == 0)
    const int bnb = bid & 7, bmb = bid >> 3;
    const int bn = bnb * 96;

    // --- B staging: wave w<6 stages one 1KB group per tile ---
    const int qch = (lane & 3) ^ ((lane >> 3) & 3);
    const u16* gBsrc = Bh + (size_t)(bn + w * 16 + (lane >> 2)) * 768 + qch * 8;

    // --- A staging: wave w stages mblk (bmb*8 + w); contiguous 1KB per tile ---
    const int mblk0 = bmb * 8 + wr * 2;          // wave's compute mblks
    const u16* gAstage = Ah + (size_t)(bmb * 8 + w) * 12288 + lane * 8;

    f32x4 acc[2][3];
    #pragma unroll
    for (int i = 0; i < 2; ++i)
        #pragma unroll
        for (int j = 0; j < 3; ++j)
            acc[i][j] = (f32x4){0.f, 0.f, 0.f, 0.f};

    // prologue: A0, B0, A1, B1
    gload_lds16(gAstage, lds + w * 512);
    if (w < 6) gload_lds16(gBsrc, lds + 12288 + w * 512);
    gload_lds16(gAstage + 512, lds + 4096 + w * 512);
    if (w < 6) gload_lds16(gBsrc + 32, lds + 12288 + 3072 + w * 512);

    const int pB = (lh ^ ((lr >> 1) & 3)) << 3;  // B frag phys chunk offset (u16)
    const int aOff0 = (wr * 2) * 512 + lane * 8; // A frag offsets in buf
    const int aOff1 = (wr * 2 + 1) * 512 + lane * 8;

// One K-step. C = compile-time phase (t_ % 3). Single barrier; stage after.
#define GEMM_ITER(C)                                                          \
    {                                                                         \
        const int t_ = 3 * tt + (C);                                          \
        if (t_ <= 22) {                                                       \
            if (w < 6) asm volatile("s_waitcnt vmcnt(2)" ::: "memory");       \
            else       asm volatile("s_waitcnt vmcnt(1)" ::: "memory");       \
        } else {                                                              \
            asm volatile("s_waitcnt vmcnt(0)" ::: "memory");                  \
        }                                                                     \
        __builtin_amdgcn_s_barrier();                                         \
        __builtin_amdgcn_sched_barrier(0);                                    \
        if (t_ <= 21) {                                                       \
            gload_lds16(gAstage + (t_ + 2) * 512,                             \
                        lds + (((C) + 2) % 3) * 4096 + w * 512);              \
            if (w < 6)                                                        \
                gload_lds16(gBsrc + (t_ + 2) * 32,                            \
                            lds + 12288 + (((C) + 2) % 3) * 3072 + w * 512);  \
        }                                                                     \
        const u16* La = lds + ((C) % 3) * 4096;                               \
        const u16* Lb = lds + 12288 + ((C) % 3) * 3072;                       \
        short8 aF[2], bF[3];                                                  \
        aF[0] = *(const short8*)&La[aOff0];                                   \
        aF[1] = *(const short8*)&La[aOff1];                                   \
        _Pragma("unroll")                                                     \
        for (int f = 0; f < 3; ++f)                                           \
            bF[f] = *(const short8*)&Lb[(wc * 48 + f * 16 + lr) * 32 + pB];   \
        __builtin_amdgcn_s_setprio(1);                                        \
        _Pragma("unroll")                                                     \
        for (int mf = 0; mf < 2; ++mf)                                        \
            _Pragma("unroll")                                                 \
            for (int nf = 0; nf < 3; ++nf)                                    \
                acc[mf][nf] = __builtin_amdgcn_mfma_f32_16x16x32_f16(aF[mf], bF[nf], acc[mf][nf], 0, 0, 0); \
        __builtin_amdgcn_s_setprio(0);                                        \
    }

    for (int tt = 0; tt < 8; ++tt) {
        GEMM_ITER(0)
        GEMM_ITER(1)
        GEMM_ITER(2)
    }
#undef GEMM_ITER

    if (MODE == 0) {
        #pragma unroll
        for (int mf = 0; mf < 2; ++mf) {
            const int mblk = mblk0 + mf;
            #pragma unroll
            for (int r = 0; r < 4; ++r) {
                const int lane_r = lh * 4 + r;
                #pragma unroll
                for (int nf = 0; nf < 3; ++nf) {
                    const int c = bn + wc * 48 + nf * 16 + lr;
                    const int idx = (mblk * 24 + (c >> 5)) * 512
                                  + ((c >> 3) & 3) * 128 + lane_r * 8 + (c & 7);
                    Oh[idx] = f2h(fmaxf(acc[mf][nf][r], 0.f));
                }
            }
        }
        return;
    }

    // ---------------- MODE 1: phase 2 (adjacency GEMM) ----------------------
    // drain: all waves done reading the K-loop buffers before hwT overwrites
    __builtin_amdgcn_s_barrier();
    __builtin_amdgcn_sched_barrier(0);

    // adj fragments straight to VGPRs (once per block)
    const u16* adjb = ADJ + (size_t)bmb * (N_ * N_);
    short8 adjr[8];
    #pragma unroll
    for (int mf = 0; mf < 2; ++mf)
        #pragma unroll
        for (int ks = 0; ks < 4; ++ks)
            adjr[mf * 4 + ks] = *(const short8*)(adjb +
                (size_t)(wr * 32 + mf * 16 + lr) * 128 + ks * 32 + lh * 8);

    // write H^T (single fp16) into LDS [c 96][node 128], chunk-swizzled
    u16* hwT = lds;
    #pragma unroll
    for (int mf = 0; mf < 2; ++mf) {
        const int node0 = wr * 32 + mf * 16 + lh * 4;
        #pragma unroll
        for (int nf = 0; nf < 3; ++nf) {
            const int c = wc * 48 + nf * 16 + lr;
            u16x4 hv;
            #pragma unroll
            for (int r = 0; r < 4; ++r) hv[r] = f2h(acc[mf][nf][r]);
            *(u16x4*)&hwT[c * 128 + (((node0 >> 3) ^ (c & 7)) << 3) + (node0 & 7)] = hv;
        }
    }
    asm volatile("s_waitcnt lgkmcnt(0)" ::: "memory");
    __builtin_amdgcn_s_barrier();
    __builtin_amdgcn_sched_barrier(0);

    f32x4 acc2[2][3];
    #pragma unroll
    for (int i = 0; i < 2; ++i)
        #pragma unroll
        for (int j = 0; j < 3; ++j)
            acc2[i][j] = (f32x4){0.f, 0.f, 0.f, 0.f};

    #pragma unroll
    for (int ks = 0; ks < 4; ++ks) {
        short8 bf[3];
        #pragma unroll
        for (int f = 0; f < 3; ++f) {
            const int c = wc * 48 + f * 16 + lr;
            bf[f] = *(const short8*)&hwT[c * 128 + (((ks * 4 + lh) ^ (c & 7)) << 3)];
        }
        #pragma unroll
        for (int mf = 0; mf < 2; ++mf)
            #pragma unroll
            for (int nf = 0; nf < 3; ++nf)
                acc2[mf][nf] = __builtin_amdgcn_mfma_f32_16x16x32_f16(adjr[mf * 4 + ks], bf[nf], acc2[mf][nf], 0, 0, 0);
    }

    // epilogue: out = relu(acc2*inv + bias) + X_in; store single fp16 FRAG
    #pragma unroll
    for (int mf = 0; mf < 2; ++mf) {
        const int mblk = mblk0 + mf;
        #pragma unroll
        for (int r = 0; r < 4; ++r) {
            const int node = wr * 32 + mf * 16 + lh * 4 + r;
            const int lane_r = lh * 4 + r;
            const float inv = invden[bmb * N_ + node];
            #pragma unroll
            for (int nf = 0; nf < 3; ++nf) {
                const int c = bn + wc * 48 + nf * 16 + lr;
                const int idx = (mblk * 24 + (c >> 5)) * 512
                              + ((c >> 3) & 3) * 128 + lane_r * 8 + (c & 7);
                float v = fmaxf(acc2[mf][nf][r] * inv + bias[c], 0.f);
                v += h2f(Ah[idx]);                  // residual = A-source
                Oh[idx] = f2h(v);
            }
        }
    }
}

// ---------------------------------------------------------------------------
// gcn_target: grid (64, 4); block covers 192 cols of batch b.
__global__ __launch_bounds__(192)
void gcn_target_kernel(const u16* __restrict__ Xh,
                       const int* __restrict__ gspan, float* __restrict__ gt) {
    const int b = blockIdx.x;
    const int c = blockIdx.y * 192 + threadIdx.x;
    const int s = gspan[b * 2 + 0];
    const int e = gspan[b * 2 + 1];
    float acc = 0.f;
    for (int n = s; n < e; ++n)
        acc += h2f(Xh[fragIdx(b * N_ + n, c)]);
    gt[(size_t)b * D_ + c] = acc;
}

// ---------------------------------------------------------------------------
__global__ __launch_bounds__(256)
void head_kernel(const float* __restrict__ tmax, const float* __restrict__ gt,
                 const float* __restrict__ fcW, const float* __restrict__ fcb,
                 float* __restrict__ out) {
    const int b = blockIdx.x;
    const int t = threadIdx.x;
    float p0 = 0.f, p1 = 0.f, p2 = 0.f;
    for (int i = t; i < 2 * D_; i += 256) {
        const float v = (i < D_) ? tmax[(size_t)b * D_ + i] : gt[(size_t)b * D_ + i - D_];
        p0 += v * fcW[i * 3 + 0];
        p1 += v * fcW[i * 3 + 1];
        p2 += v * fcW[i * 3 + 2];
    }
    #pragma unroll
    for (int off = 32; off; off >>= 1) {
        p0 += __shfl_down(p0, off, 64);
        p1 += __shfl_down(p1, off, 64);
        p2 += __shfl_down(p2, off, 64);
    }
    __shared__ float red[4][3];
    const int wv = t >> 6;
    if ((t & 63) == 0) { red[wv][0] = p0; red[wv][1] = p1; red[wv][2] = p2; }
    __syncthreads();
    if (t == 0) {
        #pragma unroll
        for (int o = 0; o < 3; ++o) {
            const float s = red[0][o] + red[1][o] + red[2][o] + red[3][o] + fcb[o];
            out[b * 3 + o] = tanhf(s);
        }
    }
}

// ---------------------------------------------------------------------------
extern "C" void kernel_launch(void* const* d_in, const int* in_sizes, int n_in,
                              void* d_out, int out_size, void* d_ws, size_t ws_size,
                              hipStream_t stream) {
    const float* se   = (const float*)d_in[0];
    const float* dg   = (const float*)d_in[1];
    const float* dg1  = (const float*)d_in[2];
    const float* Wp   = (const float*)d_in[3];
    const float* Wg[3] = {(const float*)d_in[4], (const float*)d_in[6], (const float*)d_in[8]};
    const float* bg[3] = {(const float*)d_in[5], (const float*)d_in[7], (const float*)d_in[9]};
    const float* fcW  = (const float*)d_in[10];
    const float* fcb  = (const float*)d_in[11];
    const int*   tspan  = (const int*)d_in[12];
    const int*   nspans = (const int*)d_in[13];
    const int*   gspan  = (const int*)d_in[14];
    float* out = (float*)d_out;

    // workspace layout (u16 units unless noted)
    u16* us   = (u16*)d_ws;
    u16* X0   = us;                        // 8192*768 (FRAG layout, fp16)
    u16* X1   = X0 + 6291456;
    u16* TH   = X1 + 6291456;              // tmps (FRAG layout, fp16)
    u16* WTh  = TH + 6291456;              // 4*768*768 fp16
    u16* ADJ  = WTh + 2359296;             // 64*128*128 fp16
    float* INV = (float*)(ADJ + 1048576);  // 8192
    float* TMX = INV + 8192;               // 64*768
    float* GT  = TMX + 49152;              // 64*768

    // Stage A: ragged prep
    span_split_kernel<<<B_ * N_, 192, 0, stream>>>(se, nspans, TH);
    target_max_kernel<<<dim3(B_, 4), 192, 0, stream>>>(se, tspan, TMX);
    adj_kernel<<<B_ * N_, 128, 0, stream>>>(dg, dg1, ADJ, INV);
    wsplit_kernel<<<dim3(12, 12, 4), 256, 0, stream>>>(Wp, Wg[0], Wg[1], Wg[2], WTh);

    // Stage B: X0 = relu(tmps @ W_proj)   (512 blocks: 64 row-panels x 8 col-96)
    gemm_fused<0><<<512, 512, 0, stream>>>(TH, WTh,
                                           nullptr, nullptr, nullptr, X0);

    // Stage C: 3 fused GCN layers (ping-pong X0 <-> X1)
    const u16* in_[3] = {X0, X1, X0};
    u16* out_[3] = {X1, X0, X1};
    for (int l = 0; l < 3; ++l) {
        const size_t wo = (size_t)(l + 1) * D_ * D_;
        gemm_fused<1><<<512, 512, 0, stream>>>(in_[l], WTh + wo,
                                               ADJ, INV, bg[l], out_[l]);
    }

    // Stage D: ragged node-span sum + head (final X lives in X1)
    gcn_target_kernel<<<dim3(B_, 4), 192, 0, stream>>>(X1, gspan, GT);
    head_kernel<<<B_, 256, 0, stream>>>(TMX, GT, fcW, fcb, out);
}

// Round 15
// 108.654 us; speedup vs baseline: 1.3032x; 1.0158x over previous
//
#include <hip/hip_runtime.h>
#include <float.h>
#include <math.h>

typedef __attribute__((ext_vector_type(8))) short short8;
typedef __attribute__((ext_vector_type(4))) float f32x4;
typedef __attribute__((ext_vector_type(4))) unsigned short u16x4;
typedef unsigned short u16;
typedef unsigned int u32;

constexpr int B_ = 64, S_ = 512, N_ = 128, D_ = 768;

// ---------------------------------------------------------------------------
__device__ inline u16 f2h(float x) {
    _Float16 hh = (_Float16)x;
    return __builtin_bit_cast(u16, hh);
}
__device__ inline float h2f(u16 h) {
    return (float)__builtin_bit_cast(_Float16, h);
}

__device__ inline void gload_lds16(const u16* g, u16* s) {
    __builtin_amdgcn_global_load_lds(
        (const __attribute__((address_space(1))) u32*)g,
        (__attribute__((address_space(3))) u32*)s, 16, 0, 0);
}

// Fragment-major layout for activation matrices [M][768]:
// u16 index of (row, col) = ((row>>4)*24 + (col>>5))*512
//                         + ((col>>3)&3)*128 + (row&15)*8 + (col&7)
__device__ inline int fragIdx(int row, int col) {
    return ((row >> 4) * 24 + (col >> 5)) * 512 + ((col >> 3) & 3) * 128
         + (row & 15) * 8 + (col & 7);
}

// ---------------------------------------------------------------------------
// tmps[b,n,:] = sum_{r=s+1..e} se[b,r,:]  -> single fp16, FRAG layout
__global__ __launch_bounds__(192)
void span_split_kernel(const float* __restrict__ se, const int* __restrict__ spans,
                       u16* __restrict__ th) {
    const int bn = blockIdx.x;
    const int b  = bn >> 7;
    const int s  = spans[bn * 2 + 0];
    const int e  = spans[bn * 2 + 1];
    const float* base = se + (size_t)b * S_ * D_;
    const int d4 = threadIdx.x;
    float4 acc = make_float4(0.f, 0.f, 0.f, 0.f);
    for (int r = s + 1; r <= e; ++r) {
        const float4 v = reinterpret_cast<const float4*>(base + (size_t)r * D_)[d4];
        acc.x += v.x; acc.y += v.y; acc.z += v.z; acc.w += v.w;
    }
    u16x4 hv;
    hv[0] = f2h(acc.x); hv[1] = f2h(acc.y);
    hv[2] = f2h(acc.z); hv[3] = f2h(acc.w);
    *(u16x4*)(th + fragIdx(bn, d4 * 4)) = hv;
}

// ---------------------------------------------------------------------------
// target_max: grid (64, 4); block covers 192 cols of batch b.
__global__ __launch_bounds__(192)
void target_max_kernel(const float* __restrict__ se, const int* __restrict__ tspan,
                       float* __restrict__ tmax) {
    const int b = blockIdx.x;
    const int c = blockIdx.y * 192 + threadIdx.x;
    const int s = tspan[b * 2 + 0];
    const int e = tspan[b * 2 + 1];
    const float* base = se + (size_t)b * S_ * D_ + c;
    float m = -FLT_MAX;
    for (int r = s; r < e; ++r) m = fmaxf(m, base[(size_t)r * D_]);
    tmax[(size_t)b * D_ + c] = m;
}

// ---------------------------------------------------------------------------
// adj = clamp(dg+dg1,1) -> fp16 (exact {0,1}) [b][n][k]; invden = 1/(rowsum+1e-7)
__global__ __launch_bounds__(128)
void adj_kernel(const float* __restrict__ dg, const float* __restrict__ dg1,
                u16* __restrict__ adj, float* __restrict__ invden) {
    const int row = blockIdx.x;
    const int t   = threadIdx.x;
    const size_t idx = (size_t)row * N_ + t;
    float a = dg[idx] + dg1[idx];
    a = (a >= 1.f) ? 1.f : a;
    adj[idx] = f2h(a);
    float w = a;
    #pragma unroll
    for (int off = 32; off; off >>= 1) w += __shfl_down(w, off, 64);
    __shared__ float ssum[2];
    if ((t & 63) == 0) ssum[t >> 6] = w;
    __syncthreads();
    if (t == 0) invden[row] = 1.f / (ssum[0] + ssum[1] + 1e-7f);
}

// ---------------------------------------------------------------------------
// Weights: W[k][n] (768x768) -> WT[n][k] single fp16. blockIdx.z = matrix.
__global__ __launch_bounds__(256)
void wsplit_kernel(const float* __restrict__ W0, const float* __restrict__ W1,
                   const float* __restrict__ W2, const float* __restrict__ W3,
                   u16* __restrict__ wth) {
    __shared__ float t[64][65];
    const int mi = blockIdx.z;
    const float* W = (mi == 0) ? W0 : (mi == 1) ? W1 : (mi == 2) ? W2 : W3;
    const int k0 = blockIdx.y * 64, n0 = blockIdx.x * 64;
    #pragma unroll 4
    for (int it = 0; it < 16; ++it) {
        const int lin = it * 256 + threadIdx.x;
        const int r = lin >> 6, c = lin & 63;
        t[r][c] = W[(size_t)(k0 + r) * D_ + n0 + c];
    }
    __syncthreads();
    u16* oh = wth + (size_t)mi * D_ * D_;
    #pragma unroll 4
    for (int it = 0; it < 16; ++it) {
        const int lin = it * 256 + threadIdx.x;
        const int r = lin >> 6, c = lin & 63;
        oh[(size_t)(n0 + r) * D_ + k0 + c] = f2h(t[c][r]);
    }
}

// ---------------------------------------------------------------------------
// Fused fp16 GEMM (H ~= A @ W, all single fp16 storage).
// 128x96 tile, BK=64 (12 K-iterations), 8 waves (4x2), 512 blocks (2/CU).
// LDS 56 KB: A dbuf 2x16KB [0,16384) u16 | B dbuf 2x12KB [16384,28672) u16.
// Single barrier per K-step; stage-after-barrier into buf (t+1)&1 (safe:
// reads of that buf completed before barrier t); vmcnt(0) at iter top waits
// only on own tile-t staging issued a full iteration earlier.
// MODE 0: store relu(H) single fp16, FRAG layout.
// MODE 1: out = relu((adj[b]@H)*invden + bias) + X_in (FRAG layout);
//   adj in VGPRs post-loop; hwT (24 KB) overlays A region after a drain.
template<int MODE>
__global__ __launch_bounds__(512, 4)
void gemm_fused(const u16* __restrict__ Ah,
                const u16* __restrict__ Bh,
                const u16* __restrict__ ADJ, const float* __restrict__ invden,
                const float* __restrict__ bias,
                u16* __restrict__ Oh) {
    __shared__ u16 lds[28672];   // A dbuf [0,16384) | B dbuf [16384,28672)
    const int tid  = threadIdx.x;
    const int lane = tid & 63, w = tid >> 6;     // 8 waves
    const int wr = w >> 1, wc = w & 1;           // 4 row x 2 col
    const int lr = lane & 15, lh = lane >> 4;

    int bid = blockIdx.x;
    bid = (bid & 7) * 64 + (bid >> 3);           // XCD swizzle (512 % 8 == 0)
    const int bnb = bid & 7, bmb = bid >> 3;
    const int bn = bnb * 96;

    // --- B staging: wave w<6 stages rows w*16..w*16+15, both 32-k slices ---
    const int qch = (lane & 3) ^ ((lane >> 3) & 3);
    const u16* gBsrc = Bh + (size_t)(bn + w * 16 + (lane >> 2)) * 768 + qch * 8;

    // --- A staging: wave w stages mblk (bmb*8 + w), both slices (1KB each) ---
    const int mblk0 = bmb * 8 + wr * 2;          // wave's compute mblks
    const u16* gAstage = Ah + (size_t)(bmb * 8 + w) * 12288 + lane * 8;

    f32x4 acc[2][3];
    #pragma unroll
    for (int i = 0; i < 2; ++i)
        #pragma unroll
        for (int j = 0; j < 3; ++j)
            acc[i][j] = (f32x4){0.f, 0.f, 0.f, 0.f};

    // prologue: stage K-tile 0 into buf0 (A: 2 slices; B: 2 slices for w<6)
    gload_lds16(gAstage,       lds + w * 1024);
    gload_lds16(gAstage + 512, lds + w * 1024 + 512);
    if (w < 6) {
        gload_lds16(gBsrc,      lds + 16384 + w * 512);
        gload_lds16(gBsrc + 32, lds + 16384 + 3072 + w * 512);
    }

    const int pB = (lh ^ ((lr >> 1) & 3)) << 3;  // B frag phys chunk offset (u16)

// One K-step (64 wide). C = compile-time phase (t_ & 1).
#define GEMM_ITER(C)                                                          \
    {                                                                         \
        const int t_ = 2 * tt + (C);                                          \
        asm volatile("s_waitcnt vmcnt(0)" ::: "memory");                      \
        __builtin_amdgcn_s_barrier();                                         \
        __builtin_amdgcn_sched_barrier(0);                                    \
        if (t_ <= 10) {                                                       \
            u16* ab = lds + (((C) + 1) & 1) * 8192;                           \
            gload_lds16(gAstage + (2 * (t_ + 1)) * 512,     ab + w * 1024);   \
            gload_lds16(gAstage + (2 * (t_ + 1) + 1) * 512, ab + w * 1024 + 512); \
            if (w < 6) {                                                      \
                u16* bb = lds + 16384 + (((C) + 1) & 1) * 6144;               \
                gload_lds16(gBsrc + (t_ + 1) * 64,      bb + w * 512);        \
                gload_lds16(gBsrc + (t_ + 1) * 64 + 32, bb + 3072 + w * 512); \
            }                                                                 \
        }                                                                     \
        const u16* La = lds + ((C) & 1) * 8192;                               \
        const u16* Lb = lds + 16384 + ((C) & 1) * 6144;                       \
        short8 aF[2][2], bF[3][2];                                            \
        _Pragma("unroll")                                                     \
        for (int sl = 0; sl < 2; ++sl) {                                      \
            aF[0][sl] = *(const short8*)&La[(wr * 2) * 1024 + sl * 512 + lane * 8];     \
            aF[1][sl] = *(const short8*)&La[(wr * 2 + 1) * 1024 + sl * 512 + lane * 8]; \
            _Pragma("unroll")                                                 \
            for (int f = 0; f < 3; ++f)                                       \
                bF[f][sl] = *(const short8*)&Lb[sl * 3072 + (wc * 48 + f * 16 + lr) * 32 + pB]; \
        }                                                                     \
        __builtin_amdgcn_s_setprio(1);                                        \
        _Pragma("unroll")                                                     \
        for (int sl = 0; sl < 2; ++sl)                                        \
            _Pragma("unroll")                                                 \
            for (int mf = 0; mf < 2; ++mf)                                    \
                _Pragma("unroll")                                             \
                for (int nf = 0; nf < 3; ++nf)                                \
                    acc[mf][nf] = __builtin_amdgcn_mfma_f32_16x16x32_f16(aF[mf][sl], bF[nf][sl], acc[mf][nf], 0, 0, 0); \
        __builtin_amdgcn_s_setprio(0);                                        \
    }

    for (int tt = 0; tt < 6; ++tt) {
        GEMM_ITER(0)
        GEMM_ITER(1)
    }
#undef GEMM_ITER

    if (MODE == 0) {
        #pragma unroll
        for (int mf = 0; mf < 2; ++mf) {
            const int mblk = mblk0 + mf;
            #pragma unroll
            for (int r = 0; r < 4; ++r) {
                const int lane_r = lh * 4 + r;
                #pragma unroll
                for (int nf = 0; nf < 3; ++nf) {
                    const int c = bn + wc * 48 + nf * 16 + lr;
                    const int idx = (mblk * 24 + (c >> 5)) * 512
                                  + ((c >> 3) & 3) * 128 + lane_r * 8 + (c & 7);
                    Oh[idx] = f2h(fmaxf(acc[mf][nf][r], 0.f));
                }
            }
        }
        return;
    }

    // ---------------- MODE 1: phase 2 (adjacency GEMM) ----------------------
    // drain: all waves done reading the K-loop buffers before hwT overwrites
    __builtin_amdgcn_s_barrier();
    __builtin_amdgcn_sched_barrier(0);

    // adj fragments straight to VGPRs (once per block)
    const u16* adjb = ADJ + (size_t)bmb * (N_ * N_);
    short8 adjr[8];
    #pragma unroll
    for (int mf = 0; mf < 2; ++mf)
        #pragma unroll
        for (int ks = 0; ks < 4; ++ks)
            adjr[mf * 4 + ks] = *(const short8*)(adjb +
                (size_t)(wr * 32 + mf * 16 + lr) * 128 + ks * 32 + lh * 8);

    // write H^T (single fp16) into LDS [c 96][node 128], chunk-swizzled
    u16* hwT = lds;
    #pragma unroll
    for (int mf = 0; mf < 2; ++mf) {
        const int node0 = wr * 32 + mf * 16 + lh * 4;
        #pragma unroll
        for (int nf = 0; nf < 3; ++nf) {
            const int c = wc * 48 + nf * 16 + lr;
            u16x4 hv;
            #pragma unroll
            for (int r = 0; r < 4; ++r) hv[r] = f2h(acc[mf][nf][r]);
            *(u16x4*)&hwT[c * 128 + (((node0 >> 3) ^ (c & 7)) << 3) + (node0 & 7)] = hv;
        }
    }
    asm volatile("s_waitcnt lgkmcnt(0)" ::: "memory");
    __builtin_amdgcn_s_barrier();
    __builtin_amdgcn_sched_barrier(0);

    f32x4 acc2[2][3];
    #pragma unroll
    for (int i = 0; i < 2; ++i)
        #pragma unroll
        for (int j = 0; j < 3; ++j)
            acc2[i][j] = (f32x4){0.f, 0.f, 0.f, 0.f};

    #pragma unroll
    for (int ks = 0; ks < 4; ++ks) {
        short8 bf[3];
        #pragma unroll
        for (int f = 0; f < 3; ++f) {
            const int c = wc * 48 + f * 16 + lr;
            bf[f] = *(const short8*)&hwT[c * 128 + (((ks * 4 + lh) ^ (c & 7)) << 3)];
        }
        #pragma unroll
        for (int mf = 0; mf < 2; ++mf)
            #pragma unroll
            for (int nf = 0; nf < 3; ++nf)
                acc2[mf][nf] = __builtin_amdgcn_mfma_f32_16x16x32_f16(adjr[mf * 4 + ks], bf[nf], acc2[mf][nf], 0, 0, 0);
    }

    // epilogue: out = relu(acc2*inv + bias) + X_in; store single fp16 FRAG
    #pragma unroll
    for (int mf = 0; mf < 2; ++mf) {
        const int mblk = mblk0 + mf;
        #pragma unroll
        for (int r = 0; r < 4; ++r) {
            const int node = wr * 32 + mf * 16 + lh * 4 + r;
            const int lane_r = lh * 4 + r;
            const float inv = invden[bmb * N_ + node];
            #pragma unroll
            for (int nf = 0; nf < 3; ++nf) {
                const int c = bn + wc * 48 + nf * 16 + lr;
                const int idx = (mblk * 24 + (c >> 5)) * 512
                              + ((c >> 3) & 3) * 128 + lane_r * 8 + (c & 7);
                float v = fmaxf(acc2[mf][nf][r] * inv + bias[c], 0.f);
                v += h2f(Ah[idx]);                  // residual = A-source
                Oh[idx] = f2h(v);
            }
        }
    }
}

// ---------------------------------------------------------------------------
// gcn_target: grid (64, 4); block covers 192 cols of batch b.
__global__ __launch_bounds__(192)
void gcn_target_kernel(const u16* __restrict__ Xh,
                       const int* __restrict__ gspan, float* __restrict__ gt) {
    const int b = blockIdx.x;
    const int c = blockIdx.y * 192 + threadIdx.x;
    const int s = gspan[b * 2 + 0];
    const int e = gspan[b * 2 + 1];
    float acc = 0.f;
    for (int n = s; n < e; ++n)
        acc += h2f(Xh[fragIdx(b * N_ + n, c)]);
    gt[(size_t)b * D_ + c] = acc;
}

// ---------------------------------------------------------------------------
__global__ __launch_bounds__(256)
void head_kernel(const float* __restrict__ tmax, const float* __restrict__ gt,
                 const float* __restrict__ fcW, const float* __restrict__ fcb,
                 float* __restrict__ out) {
    const int b = blockIdx.x;
    const int t = threadIdx.x;
    float p0 = 0.f, p1 = 0.f, p2 = 0.f;
    for (int i = t; i < 2 * D_; i += 256) {
        const float v = (i < D_) ? tmax[(size_t)b * D_ + i] : gt[(size_t)b * D_ + i - D_];
        p0 += v * fcW[i * 3 + 0];
        p1 += v * fcW[i * 3 + 1];
        p2 += v * fcW[i * 3 + 2];
    }
    #pragma unroll
    for (int off = 32; off; off >>= 1) {
        p0 += __shfl_down(p0, off, 64);
        p1 += __shfl_down(p1, off, 64);
        p2 += __shfl_down(p2, off, 64);
    }
    __shared__ float red[4][3];
    const int wv = t >> 6;
    if ((t & 63) == 0) { red[wv][0] = p0; red[wv][1] = p1; red[wv][2] = p2; }
    __syncthreads();
    if (t == 0) {
        #pragma unroll
        for (int o = 0; o < 3; ++o) {
            const float s = red[0][o] + red[1][o] + red[2][o] + red[3][o] + fcb[o];
            out[b * 3 + o] = tanhf(s);
        }
    }
}

// ---------------------------------------------------------------------------
extern "C" void kernel_launch(void* const* d_in, const int* in_sizes, int n_in,
                              void* d_out, int out_size, void* d_ws, size_t ws_size,
                              hipStream_t stream) {
    const float* se   = (const float*)d_in[0];
    const float* dg   = (const float*)d_in[1];
    const float* dg1  = (const float*)d_in[2];
    const float* Wp   = (const float*)d_in[3];
    const float* Wg[3] = {(const float*)d_in[4], (const float*)d_in[6], (const float*)d_in[8]};
    const float* bg[3] = {(const float*)d_in[5], (const float*)d_in[7], (const float*)d_in[9]};
    const float* fcW  = (const float*)d_in[10];
    const float* fcb  = (const float*)d_in[11];
    const int*   tspan  = (const int*)d_in[12];
    const int*   nspans = (const int*)d_in[13];
    const int*   gspan  = (const int*)d_in[14];
    float* out = (float*)d_out;

    // workspace layout (u16 units unless noted)
    u16* us   = (u16*)d_ws;
    u16* X0   = us;                        // 8192*768 (FRAG layout, fp16)
    u16* X1   = X0 + 6291456;
    u16* TH   = X1 + 6291456;              // tmps (FRAG layout, fp16)
    u16* WTh  = TH + 6291456;              // 4*768*768 fp16
    u16* ADJ  = WTh + 2359296;             // 64*128*128 fp16
    float* INV = (float*)(ADJ + 1048576);  // 8192
    float* TMX = INV + 8192;               // 64*768
    float* GT  = TMX + 49152;              // 64*768

    // Stage A: ragged prep
    span_split_kernel<<<B_ * N_, 192, 0, stream>>>(se, nspans, TH);
    target_max_kernel<<<dim3(B_, 4), 192, 0, stream>>>(se, tspan, TMX);
    adj_kernel<<<B_ * N_, 128, 0, stream>>>(dg, dg1, ADJ, INV);
    wsplit_kernel<<<dim3(12, 12, 4), 256, 0, stream>>>(Wp, Wg[0], Wg[1], Wg[2], WTh);

    // Stage B: X0 = relu(tmps @ W_proj)   (512 blocks: 64 row-panels x 8 col-96)
    gemm_fused<0><<<512, 512, 0, stream>>>(TH, WTh,
                                           nullptr, nullptr, nullptr, X0);

    // Stage C: 3 fused GCN layers (ping-pong X0 <-> X1)
    const u16* in_[3] = {X0, X1, X0};
    u16* out_[3] = {X1, X0, X1};
    for (int l = 0; l < 3; ++l) {
        const size_t wo = (size_t)(l + 1) * D_ * D_;
        gemm_fused<1><<<512, 512, 0, stream>>>(in_[l], WTh + wo,
                                               ADJ, INV, bg[l], out_[l]);
    }

    // Stage D: ragged node-span sum + head (final X lives in X1)
    gcn_target_kernel<<<dim3(B_, 4), 192, 0, stream>>>(X1, gspan, GT);
    head_kernel<<<B_, 256, 0, stream>>>(TMX, GT, fcW, fcb, out);
}

// Round 16
// 105.439 us; speedup vs baseline: 1.3429x; 1.0305x over previous
//
#include <hip/hip_runtime.h>
#include <float.h>
#include <math.h>

typedef __attribute__((ext_vector_type(8))) short short8;
typedef __attribute__((ext_vector_type(4))) float f32x4;
typedef __attribute__((ext_vector_type(4))) unsigned short u16x4;
typedef unsigned short u16;
typedef unsigned int u32;

constexpr int B_ = 64, S_ = 512, N_ = 128, D_ = 768;

// ---------------------------------------------------------------------------
__device__ inline u16 f2h(float x) {
    _Float16 hh = (_Float16)x;
    return __builtin_bit_cast(u16, hh);
}
__device__ inline float h2f(u16 h) {
    return (float)__builtin_bit_cast(_Float16, h);
}

__device__ inline void gload_lds16(const u16* g, u16* s) {
    __builtin_amdgcn_global_load_lds(
        (const __attribute__((address_space(1))) u32*)g,
        (__attribute__((address_space(3))) u32*)s, 16, 0, 0);
}

// Fragment-major layout for activation matrices [M][768]:
// u16 index of (row, col) = ((row>>4)*24 + (col>>5))*512
//                         + ((col>>3)&3)*128 + (row&15)*8 + (col&7)
__device__ inline int fragIdx(int row, int col) {
    return ((row >> 4) * 24 + (col >> 5)) * 512 + ((col >> 3) & 3) * 128
         + (row & 15) * 8 + (col & 7);
}

// ---------------------------------------------------------------------------
// tmps[b,n,:] = sum_{r=s+1..e} se[b,r,:]  -> single fp16, FRAG layout
__global__ __launch_bounds__(192)
void span_split_kernel(const float* __restrict__ se, const int* __restrict__ spans,
                       u16* __restrict__ th) {
    const int bn = blockIdx.x;
    const int b  = bn >> 7;
    const int s  = spans[bn * 2 + 0];
    const int e  = spans[bn * 2 + 1];
    const float* base = se + (size_t)b * S_ * D_;
    const int d4 = threadIdx.x;
    float4 acc = make_float4(0.f, 0.f, 0.f, 0.f);
    for (int r = s + 1; r <= e; ++r) {
        const float4 v = reinterpret_cast<const float4*>(base + (size_t)r * D_)[d4];
        acc.x += v.x; acc.y += v.y; acc.z += v.z; acc.w += v.w;
    }
    u16x4 hv;
    hv[0] = f2h(acc.x); hv[1] = f2h(acc.y);
    hv[2] = f2h(acc.z); hv[3] = f2h(acc.w);
    *(u16x4*)(th + fragIdx(bn, d4 * 4)) = hv;
}

// ---------------------------------------------------------------------------
// adj = clamp(dg+dg1,1) -> fp16 (exact {0,1}) [b][n][k]; invden = 1/(rowsum+1e-7)
__global__ __launch_bounds__(128)
void adj_kernel(const float* __restrict__ dg, const float* __restrict__ dg1,
                u16* __restrict__ adj, float* __restrict__ invden) {
    const int row = blockIdx.x;
    const int t   = threadIdx.x;
    const size_t idx = (size_t)row * N_ + t;
    float a = dg[idx] + dg1[idx];
    a = (a >= 1.f) ? 1.f : a;
    adj[idx] = f2h(a);
    float w = a;
    #pragma unroll
    for (int off = 32; off; off >>= 1) w += __shfl_down(w, off, 64);
    __shared__ float ssum[2];
    if ((t & 63) == 0) ssum[t >> 6] = w;
    __syncthreads();
    if (t == 0) invden[row] = 1.f / (ssum[0] + ssum[1] + 1e-7f);
}

// ---------------------------------------------------------------------------
// Weights: W[k][n] (768x768) -> WT[n][k] single fp16. blockIdx.z = matrix.
__global__ __launch_bounds__(256)
void wsplit_kernel(const float* __restrict__ W0, const float* __restrict__ W1,
                   const float* __restrict__ W2, const float* __restrict__ W3,
                   u16* __restrict__ wth) {
    __shared__ float t[64][65];
    const int mi = blockIdx.z;
    const float* W = (mi == 0) ? W0 : (mi == 1) ? W1 : (mi == 2) ? W2 : W3;
    const int k0 = blockIdx.y * 64, n0 = blockIdx.x * 64;
    #pragma unroll 4
    for (int it = 0; it < 16; ++it) {
        const int lin = it * 256 + threadIdx.x;
        const int r = lin >> 6, c = lin & 63;
        t[r][c] = W[(size_t)(k0 + r) * D_ + n0 + c];
    }
    __syncthreads();
    u16* oh = wth + (size_t)mi * D_ * D_;
    #pragma unroll 4
    for (int it = 0; it < 16; ++it) {
        const int lin = it * 256 + threadIdx.x;
        const int r = lin >> 6, c = lin & 63;
        oh[(size_t)(n0 + r) * D_ + k0 + c] = f2h(t[c][r]);
    }
}

// ---------------------------------------------------------------------------
// Fused fp16 GEMM (H ~= A @ W, all single fp16 storage).
// 128x96 tile, BK=64 (12 K-iterations), 8 waves (4x2), 512 blocks (2/CU).
// LDS 56 KB: A dbuf 2x16KB [0,16384) u16 | B dbuf 2x12KB [16384,28672) u16.
// Single barrier per K-step; stage-after-barrier into buf (t+1)&1.
// MODE 0: store relu(H) single fp16, FRAG layout.
// MODE 1: out = relu((adj[b]@H)*invden + bias) + X_in (FRAG layout).
// MODE 2: as MODE 1, but final layer: do NOT store X; instead compute the
//   gcn_span-masked node-sum per column in-register, reduce via LDS
//   [96][16] (deterministic fixed-order), write GT[b][bn..bn+95].
template<int MODE>
__global__ __launch_bounds__(512, 4)
void gemm_fused(const u16* __restrict__ Ah,
                const u16* __restrict__ Bh,
                const u16* __restrict__ ADJ, const float* __restrict__ invden,
                const float* __restrict__ bias,
                u16* __restrict__ Oh,
                const int* __restrict__ gspan, float* __restrict__ GT) {
    __shared__ u16 lds[28672];   // A dbuf [0,16384) | B dbuf [16384,28672)
    const int tid  = threadIdx.x;
    const int lane = tid & 63, w = tid >> 6;     // 8 waves
    const int wr = w >> 1, wc = w & 1;           // 4 row x 2 col
    const int lr = lane & 15, lh = lane >> 4;

    int bid = blockIdx.x;
    bid = (bid & 7) * 64 + (bid >> 3);           // XCD swizzle (512 % 8 == 0)
    const int bnb = bid & 7, bmb = bid >> 3;
    const int bn = bnb * 96;

    // --- B staging: wave w<6 stages rows w*16..w*16+15, both 32-k slices ---
    const int qch = (lane & 3) ^ ((lane >> 3) & 3);
    const u16* gBsrc = Bh + (size_t)(bn + w * 16 + (lane >> 2)) * 768 + qch * 8;

    // --- A staging: wave w stages mblk (bmb*8 + w), both slices (1KB each) ---
    const int mblk0 = bmb * 8 + wr * 2;          // wave's compute mblks
    const u16* gAstage = Ah + (size_t)(bmb * 8 + w) * 12288 + lane * 8;

    f32x4 acc[2][3];
    #pragma unroll
    for (int i = 0; i < 2; ++i)
        #pragma unroll
        for (int j = 0; j < 3; ++j)
            acc[i][j] = (f32x4){0.f, 0.f, 0.f, 0.f};

    // prologue: stage K-tile 0 into buf0 (A: 2 slices; B: 2 slices for w<6)
    gload_lds16(gAstage,       lds + w * 1024);
    gload_lds16(gAstage + 512, lds + w * 1024 + 512);
    if (w < 6) {
        gload_lds16(gBsrc,      lds + 16384 + w * 512);
        gload_lds16(gBsrc + 32, lds + 16384 + 3072 + w * 512);
    }

    const int pB = (lh ^ ((lr >> 1) & 3)) << 3;  // B frag phys chunk offset (u16)

// One K-step (64 wide). C = compile-time phase (t_ & 1).
#define GEMM_ITER(C)                                                          \
    {                                                                         \
        const int t_ = 2 * tt + (C);                                          \
        asm volatile("s_waitcnt vmcnt(0)" ::: "memory");                      \
        __builtin_amdgcn_s_barrier();                                         \
        __builtin_amdgcn_sched_barrier(0);                                    \
        if (t_ <= 10) {                                                       \
            u16* ab = lds + (((C) + 1) & 1) * 8192;                           \
            gload_lds16(gAstage + (2 * (t_ + 1)) * 512,     ab + w * 1024);   \
            gload_lds16(gAstage + (2 * (t_ + 1) + 1) * 512, ab + w * 1024 + 512); \
            if (w < 6) {                                                      \
                u16* bb = lds + 16384 + (((C) + 1) & 1) * 6144;               \
                gload_lds16(gBsrc + (t_ + 1) * 64,      bb + w * 512);        \
                gload_lds16(gBsrc + (t_ + 1) * 64 + 32, bb + 3072 + w * 512); \
            }                                                                 \
        }                                                                     \
        const u16* La = lds + ((C) & 1) * 8192;                               \
        const u16* Lb = lds + 16384 + ((C) & 1) * 6144;                       \
        short8 aF[2][2], bF[3][2];                                            \
        _Pragma("unroll")                                                     \
        for (int sl = 0; sl < 2; ++sl) {                                      \
            aF[0][sl] = *(const short8*)&La[(wr * 2) * 1024 + sl * 512 + lane * 8];     \
            aF[1][sl] = *(const short8*)&La[(wr * 2 + 1) * 1024 + sl * 512 + lane * 8]; \
            _Pragma("unroll")                                                 \
            for (int f = 0; f < 3; ++f)                                       \
                bF[f][sl] = *(const short8*)&Lb[sl * 3072 + (wc * 48 + f * 16 + lr) * 32 + pB]; \
        }                                                                     \
        __builtin_amdgcn_s_setprio(1);                                        \
        _Pragma("unroll")                                                     \
        for (int sl = 0; sl < 2; ++sl)                                        \
            _Pragma("unroll")                                                 \
            for (int mf = 0; mf < 2; ++mf)                                    \
                _Pragma("unroll")                                             \
                for (int nf = 0; nf < 3; ++nf)                                \
                    acc[mf][nf] = __builtin_amdgcn_mfma_f32_16x16x32_f16(aF[mf][sl], bF[nf][sl], acc[mf][nf], 0, 0, 0); \
        __builtin_amdgcn_s_setprio(0);                                        \
    }

    for (int tt = 0; tt < 6; ++tt) {
        GEMM_ITER(0)
        GEMM_ITER(1)
    }
#undef GEMM_ITER

    if (MODE == 0) {
        #pragma unroll
        for (int mf = 0; mf < 2; ++mf) {
            const int mblk = mblk0 + mf;
            #pragma unroll
            for (int r = 0; r < 4; ++r) {
                const int lane_r = lh * 4 + r;
                #pragma unroll
                for (int nf = 0; nf < 3; ++nf) {
                    const int c = bn + wc * 48 + nf * 16 + lr;
                    const int idx = (mblk * 24 + (c >> 5)) * 512
                                  + ((c >> 3) & 3) * 128 + lane_r * 8 + (c & 7);
                    Oh[idx] = f2h(fmaxf(acc[mf][nf][r], 0.f));
                }
            }
        }
        return;
    }

    // ---------------- MODE 1/2: phase 2 (adjacency GEMM) --------------------
    // drain: all waves done reading the K-loop buffers before hwT overwrites
    __builtin_amdgcn_s_barrier();
    __builtin_amdgcn_sched_barrier(0);

    // adj fragments straight to VGPRs (once per block)
    const u16* adjb = ADJ + (size_t)bmb * (N_ * N_);
    short8 adjr[8];
    #pragma unroll
    for (int mf = 0; mf < 2; ++mf)
        #pragma unroll
        for (int ks = 0; ks < 4; ++ks)
            adjr[mf * 4 + ks] = *(const short8*)(adjb +
                (size_t)(wr * 32 + mf * 16 + lr) * 128 + ks * 32 + lh * 8);

    // write H^T (single fp16) into LDS [c 96][node 128], chunk-swizzled
    u16* hwT = lds;
    #pragma unroll
    for (int mf = 0; mf < 2; ++mf) {
        const int node0 = wr * 32 + mf * 16 + lh * 4;
        #pragma unroll
        for (int nf = 0; nf < 3; ++nf) {
            const int c = wc * 48 + nf * 16 + lr;
            u16x4 hv;
            #pragma unroll
            for (int r = 0; r < 4; ++r) hv[r] = f2h(acc[mf][nf][r]);
            *(u16x4*)&hwT[c * 128 + (((node0 >> 3) ^ (c & 7)) << 3) + (node0 & 7)] = hv;
        }
    }
    asm volatile("s_waitcnt lgkmcnt(0)" ::: "memory");
    __builtin_amdgcn_s_barrier();
    __builtin_amdgcn_sched_barrier(0);

    f32x4 acc2[2][3];
    #pragma unroll
    for (int i = 0; i < 2; ++i)
        #pragma unroll
        for (int j = 0; j < 3; ++j)
            acc2[i][j] = (f32x4){0.f, 0.f, 0.f, 0.f};

    #pragma unroll
    for (int ks = 0; ks < 4; ++ks) {
        short8 bf[3];
        #pragma unroll
        for (int f = 0; f < 3; ++f) {
            const int c = wc * 48 + f * 16 + lr;
            bf[f] = *(const short8*)&hwT[c * 128 + (((ks * 4 + lh) ^ (c & 7)) << 3)];
        }
        #pragma unroll
        for (int mf = 0; mf < 2; ++mf)
            #pragma unroll
            for (int nf = 0; nf < 3; ++nf)
                acc2[mf][nf] = __builtin_amdgcn_mfma_f32_16x16x32_f16(adjr[mf * 4 + ks], bf[nf], acc2[mf][nf], 0, 0, 0);
    }

    // epilogue: v = relu(acc2*inv + bias) + X_in
    // MODE 1: store v (fp16) to Oh.   MODE 2: masked column sums -> GT.
    int gs = 0, ge = 0;
    if (MODE == 2) { gs = gspan[bmb * 2 + 0]; ge = gspan[bmb * 2 + 1]; }
    float pt[3] = {0.f, 0.f, 0.f};

    #pragma unroll
    for (int mf = 0; mf < 2; ++mf) {
        const int mblk = mblk0 + mf;
        #pragma unroll
        for (int r = 0; r < 4; ++r) {
            const int node = wr * 32 + mf * 16 + lh * 4 + r;
            const int lane_r = lh * 4 + r;
            const float inv = invden[bmb * N_ + node];
            const bool in_span = (node >= gs) && (node < ge);
            #pragma unroll
            for (int nf = 0; nf < 3; ++nf) {
                const int c = bn + wc * 48 + nf * 16 + lr;
                const int idx = (mblk * 24 + (c >> 5)) * 512
                              + ((c >> 3) & 3) * 128 + lane_r * 8 + (c & 7);
                float v = fmaxf(acc2[mf][nf][r] * inv + bias[c], 0.f);
                v += h2f(Ah[idx]);                  // residual = A-source
                const u16 hv = f2h(v);
                if (MODE == 1) Oh[idx] = hv;
                else if (in_span) pt[nf] += h2f(hv);
            }
        }
    }

    if (MODE == 2) {
        // deterministic block reduction: [96 cols][16 contributors] in LDS
        float* gtbuf = (float*)(lds + 16384);    // 6 KB, B region (dead)
        const int contrib = wr * 4 + lh;         // 0..15
        #pragma unroll
        for (int nf = 0; nf < 3; ++nf)
            gtbuf[(wc * 48 + nf * 16 + lr) * 16 + contrib] = pt[nf];
        asm volatile("s_waitcnt lgkmcnt(0)" ::: "memory");
        __builtin_amdgcn_s_barrier();
        __builtin_amdgcn_sched_barrier(0);
        if (tid < 96) {
            float s = 0.f;
            #pragma unroll
            for (int i = 0; i < 16; ++i) s += gtbuf[tid * 16 + i];
            GT[(size_t)bmb * D_ + bn + tid] = s;
        }
    }
}

// ---------------------------------------------------------------------------
// head: logits = tanh(concat(target_max, gcn_target) @ fcW + fcb).
// target_max computed on the fly from se (<=15 rows per batch).
__global__ __launch_bounds__(256)
void head_kernel(const float* __restrict__ se, const int* __restrict__ tspan,
                 const float* __restrict__ gt,
                 const float* __restrict__ fcW, const float* __restrict__ fcb,
                 float* __restrict__ out) {
    const int b = blockIdx.x;
    const int t = threadIdx.x;
    const int s = tspan[b * 2 + 0];
    const int e = tspan[b * 2 + 1];
    float p0 = 0.f, p1 = 0.f, p2 = 0.f;
    for (int i = t; i < 2 * D_; i += 256) {
        float v;
        if (i < D_) {
            const float* base = se + (size_t)b * S_ * D_ + i;
            float m = -FLT_MAX;
            for (int r = s; r < e; ++r) m = fmaxf(m, base[(size_t)r * D_]);
            v = m;
        } else {
            v = gt[(size_t)b * D_ + i - D_];
        }
        p0 += v * fcW[i * 3 + 0];
        p1 += v * fcW[i * 3 + 1];
        p2 += v * fcW[i * 3 + 2];
    }
    #pragma unroll
    for (int off = 32; off; off >>= 1) {
        p0 += __shfl_down(p0, off, 64);
        p1 += __shfl_down(p1, off, 64);
        p2 += __shfl_down(p2, off, 64);
    }
    __shared__ float red[4][3];
    const int wv = t >> 6;
    if ((t & 63) == 0) { red[wv][0] = p0; red[wv][1] = p1; red[wv][2] = p2; }
    __syncthreads();
    if (t == 0) {
        #pragma unroll
        for (int o = 0; o < 3; ++o) {
            const float sacc = red[0][o] + red[1][o] + red[2][o] + red[3][o] + fcb[o];
            out[b * 3 + o] = tanhf(sacc);
        }
    }
}

// ---------------------------------------------------------------------------
extern "C" void kernel_launch(void* const* d_in, const int* in_sizes, int n_in,
                              void* d_out, int out_size, void* d_ws, size_t ws_size,
                              hipStream_t stream) {
    const float* se   = (const float*)d_in[0];
    const float* dg   = (const float*)d_in[1];
    const float* dg1  = (const float*)d_in[2];
    const float* Wp   = (const float*)d_in[3];
    const float* Wg[3] = {(const float*)d_in[4], (const float*)d_in[6], (const float*)d_in[8]};
    const float* bg[3] = {(const float*)d_in[5], (const float*)d_in[7], (const float*)d_in[9]};
    const float* fcW  = (const float*)d_in[10];
    const float* fcb  = (const float*)d_in[11];
    const int*   tspan  = (const int*)d_in[12];
    const int*   nspans = (const int*)d_in[13];
    const int*   gspan  = (const int*)d_in[14];
    float* out = (float*)d_out;

    // workspace layout (u16 units unless noted)
    u16* us   = (u16*)d_ws;
    u16* X0   = us;                        // 8192*768 (FRAG layout, fp16)
    u16* X1   = X0 + 6291456;
    u16* TH   = X1 + 6291456;              // tmps (FRAG layout, fp16)
    u16* WTh  = TH + 6291456;              // 4*768*768 fp16
    u16* ADJ  = WTh + 2359296;             // 64*128*128 fp16
    float* INV = (float*)(ADJ + 1048576);  // 8192
    float* GT  = INV + 8192;               // 64*768

    // Stage A: ragged prep
    span_split_kernel<<<B_ * N_, 192, 0, stream>>>(se, nspans, TH);
    adj_kernel<<<B_ * N_, 128, 0, stream>>>(dg, dg1, ADJ, INV);
    wsplit_kernel<<<dim3(12, 12, 4), 256, 0, stream>>>(Wp, Wg[0], Wg[1], Wg[2], WTh);

    // Stage B: X0 = relu(tmps @ W_proj)
    gemm_fused<0><<<512, 512, 0, stream>>>(TH, WTh, nullptr, nullptr, nullptr,
                                           X0, nullptr, nullptr);

    // Stage C: GCN layers 1,2 (ping-pong), layer 3 fused with gcn_target
    gemm_fused<1><<<512, 512, 0, stream>>>(X0, WTh + (size_t)1 * D_ * D_,
                                           ADJ, INV, bg[0], X1, nullptr, nullptr);
    gemm_fused<1><<<512, 512, 0, stream>>>(X1, WTh + (size_t)2 * D_ * D_,
                                           ADJ, INV, bg[1], X0, nullptr, nullptr);
    gemm_fused<2><<<512, 512, 0, stream>>>(X0, WTh + (size_t)3 * D_ * D_,
                                           ADJ, INV, bg[2], X1, gspan, GT);

    // Stage D: head (target_max computed inline)
    head_kernel<<<B_, 256, 0, stream>>>(se, tspan, GT, fcW, fcb, out);
}

// Round 18
// 103.555 us; speedup vs baseline: 1.3674x; 1.0182x over previous
//
#include <hip/hip_runtime.h>
#include <float.h>
#include <math.h>

typedef __attribute__((ext_vector_type(8))) short short8;
typedef __attribute__((ext_vector_type(4))) float f32x4;
typedef __attribute__((ext_vector_type(4))) unsigned short u16x4;
typedef unsigned short u16;
typedef unsigned int u32;

constexpr int B_ = 64, S_ = 512, N_ = 128, D_ = 768;

// ---------------------------------------------------------------------------
__device__ inline u16 f2h(float x) {
    _Float16 hh = (_Float16)x;
    return __builtin_bit_cast(u16, hh);
}
__device__ inline float h2f(u16 h) {
    return (float)__builtin_bit_cast(_Float16, h);
}

__device__ inline void gload_lds16(const u16* g, u16* s) {
    __builtin_amdgcn_global_load_lds(
        (const __attribute__((address_space(1))) u32*)g,
        (__attribute__((address_space(3))) u32*)s, 16, 0, 0);
}

// Fragment-major layout for activation matrices [M][768]:
// u16 index of (row, col) = ((row>>4)*24 + (col>>5))*512
//                         + ((col>>3)&3)*128 + (row&15)*8 + (col&7)
__device__ inline int fragIdx(int row, int col) {
    return ((row >> 4) * 24 + (col >> 5)) * 512 + ((col >> 3) & 3) * 128
         + (row & 15) * 8 + (col & 7);
}

// ---------------------------------------------------------------------------
// prep: blocks [0,8192) = span-sum -> TH (FRAG fp16);
//       blocks [8192,16384) = adj row -> ADJ fp16 + invden.
__global__ __launch_bounds__(192)
void prep_kernel(const float* __restrict__ se, const int* __restrict__ spans,
                 u16* __restrict__ th,
                 const float* __restrict__ dg, const float* __restrict__ dg1,
                 u16* __restrict__ adj, float* __restrict__ invden) {
    __shared__ float ssum[2];
    const int bid = blockIdx.x;
    if (bid < 8192) {
        const int bn = bid;
        const int b  = bn >> 7;
        const int s  = spans[bn * 2 + 0];
        const int e  = spans[bn * 2 + 1];
        const float* base = se + (size_t)b * S_ * D_;
        const int d4 = threadIdx.x;
        float4 acc = make_float4(0.f, 0.f, 0.f, 0.f);
        for (int r = s + 1; r <= e; ++r) {
            const float4 v = reinterpret_cast<const float4*>(base + (size_t)r * D_)[d4];
            acc.x += v.x; acc.y += v.y; acc.z += v.z; acc.w += v.w;
        }
        u16x4 hv;
        hv[0] = f2h(acc.x); hv[1] = f2h(acc.y);
        hv[2] = f2h(acc.z); hv[3] = f2h(acc.w);
        *(u16x4*)(th + fragIdx(bn, d4 * 4)) = hv;
    } else {
        const int row = bid - 8192;
        const int t   = threadIdx.x;
        if (t < 128) {
            const size_t idx = (size_t)row * N_ + t;
            float a = dg[idx] + dg1[idx];
            a = (a >= 1.f) ? 1.f : a;
            adj[idx] = f2h(a);
            float w = a;
            #pragma unroll
            for (int off = 32; off; off >>= 1) w += __shfl_down(w, off, 64);
            if ((t & 63) == 0) ssum[t >> 6] = w;
        }
        __syncthreads();
        if (t == 0) invden[row] = 1.f / (ssum[0] + ssum[1] + 1e-7f);
    }
}

// ---------------------------------------------------------------------------
// Weights: W[k][n] (768x768) -> WT[n][k] single fp16. blockIdx.z = matrix.
__global__ __launch_bounds__(256)
void wsplit_kernel(const float* __restrict__ W0, const float* __restrict__ W1,
                   const float* __restrict__ W2, const float* __restrict__ W3,
                   u16* __restrict__ wth) {
    __shared__ float t[64][65];
    const int mi = blockIdx.z;
    const float* W = (mi == 0) ? W0 : (mi == 1) ? W1 : (mi == 2) ? W2 : W3;
    const int k0 = blockIdx.y * 64, n0 = blockIdx.x * 64;
    #pragma unroll 4
    for (int it = 0; it < 16; ++it) {
        const int lin = it * 256 + threadIdx.x;
        const int r = lin >> 6, c = lin & 63;
        t[r][c] = W[(size_t)(k0 + r) * D_ + n0 + c];
    }
    __syncthreads();
    u16* oh = wth + (size_t)mi * D_ * D_;
    #pragma unroll 4
    for (int it = 0; it < 16; ++it) {
        const int lin = it * 256 + threadIdx.x;
        const int r = lin >> 6, c = lin & 63;
        oh[(size_t)(n0 + r) * D_ + k0 + c] = f2h(t[c][r]);
    }
}

// ---------------------------------------------------------------------------
// Fused fp16 GEMM (H ~= A @ W, all single fp16 storage).
// 128x96 tile, BK=64 (12 K-iterations), 8 waves (4x2), 512 blocks (2/CU).
// LDS 56 KB: A dbuf 2x16KB [0,16384) u16 | B dbuf 2x12KB [16384,28672) u16.
// Single barrier per K-step; stage-after-barrier into buf (t+1)&1.
// MODE 0: store relu(H) single fp16, FRAG layout.
// MODE 1: out = relu((adj[b]@H)*invden + bias) + X_in (FRAG layout).
// MODE 2: as MODE 1, but final layer: do NOT store X; instead compute the
//   gcn_span-masked node-sum per column in-register, reduce via LDS
//   [96][16] (deterministic fixed-order), write GT[b][bn..bn+95].
template<int MODE>
__global__ __launch_bounds__(512, 4)
void gemm_fused(const u16* __restrict__ Ah,
                const u16* __restrict__ Bh,
                const u16* __restrict__ ADJ, const float* __restrict__ invden,
                const float* __restrict__ bias,
                u16* __restrict__ Oh,
                const int* __restrict__ gspan, float* __restrict__ GT) {
    __shared__ u16 lds[28672];   // A dbuf [0,16384) | B dbuf [16384,28672)
    const int tid  = threadIdx.x;
    const int lane = tid & 63, w = tid >> 6;     // 8 waves
    const int wr = w >> 1, wc = w & 1;           // 4 row x 2 col
    const int lr = lane & 15, lh = lane >> 4;

    int bid = blockIdx.x;
    bid = (bid & 7) * 64 + (bid >> 3);           // XCD swizzle (512 % 8 == 0)
    const int bnb = bid & 7, bmb = bid >> 3;
    const int bn = bnb * 96;

    // --- B staging: wave w<6 stages rows w*16..w*16+15, both 32-k slices ---
    const int qch = (lane & 3) ^ ((lane >> 3) & 3);
    const u16* gBsrc = Bh + (size_t)(bn + w * 16 + (lane >> 2)) * 768 + qch * 8;

    // --- A staging: wave w stages mblk (bmb*8 + w), both slices (1KB each) ---
    const int mblk0 = bmb * 8 + wr * 2;          // wave's compute mblks
    const u16* gAstage = Ah + (size_t)(bmb * 8 + w) * 12288 + lane * 8;

    f32x4 acc[2][3];
    #pragma unroll
    for (int i = 0; i < 2; ++i)
        #pragma unroll
        for (int j = 0; j < 3; ++j)
            acc[i][j] = (f32x4){0.f, 0.f, 0.f, 0.f};

    // prologue: stage K-tile 0 into buf0 (A: 2 slices; B: 2 slices for w<6)
    gload_lds16(gAstage,       lds + w * 1024);
    gload_lds16(gAstage + 512, lds + w * 1024 + 512);
    if (w < 6) {
        gload_lds16(gBsrc,      lds + 16384 + w * 512);
        gload_lds16(gBsrc + 32, lds + 16384 + 3072 + w * 512);
    }

    const int pB = (lh ^ ((lr >> 1) & 3)) << 3;  // B frag phys chunk offset (u16)

// One K-step (64 wide). C = compile-time phase (t_ & 1).
#define GEMM_ITER(C)                                                          \
    {                                                                         \
        const int t_ = 2 * tt + (C);                                          \
        asm volatile("s_waitcnt vmcnt(0)" ::: "memory");                      \
        __builtin_amdgcn_s_barrier();                                         \
        __builtin_amdgcn_sched_barrier(0);                                    \
        if (t_ <= 10) {                                                       \
            u16* ab = lds + (((C) + 1) & 1) * 8192;                           \
            gload_lds16(gAstage + (2 * (t_ + 1)) * 512,     ab + w * 1024);   \
            gload_lds16(gAstage + (2 * (t_ + 1) + 1) * 512, ab + w * 1024 + 512); \
            if (w < 6) {                                                      \
                u16* bb = lds + 16384 + (((C) + 1) & 1) * 6144;               \
                gload_lds16(gBsrc + (t_ + 1) * 64,      bb + w * 512);        \
                gload_lds16(gBsrc + (t_ + 1) * 64 + 32, bb + 3072 + w * 512); \
            }                                                                 \
        }                                                                     \
        const u16* La = lds + ((C) & 1) * 8192;                               \
        const u16* Lb = lds + 16384 + ((C) & 1) * 6144;                       \
        short8 aF[2][2], bF[3][2];                                            \
        _Pragma("unroll")                                                     \
        for (int sl = 0; sl < 2; ++sl) {                                      \
            aF[0][sl] = *(const short8*)&La[(wr * 2) * 1024 + sl * 512 + lane * 8];     \
            aF[1][sl] = *(const short8*)&La[(wr * 2 + 1) * 1024 + sl * 512 + lane * 8]; \
            _Pragma("unroll")                                                 \
            for (int f = 0; f < 3; ++f)                                       \
                bF[f][sl] = *(const short8*)&Lb[sl * 3072 + (wc * 48 + f * 16 + lr) * 32 + pB]; \
        }                                                                     \
        __builtin_amdgcn_s_setprio(1);                                        \
        _Pragma("unroll")                                                     \
        for (int sl = 0; sl < 2; ++sl)                                        \
            _Pragma("unroll")                                                 \
            for (int mf = 0; mf < 2; ++mf)                                    \
                _Pragma("unroll")                                             \
                for (int nf = 0; nf < 3; ++nf)                                \
                    acc[mf][nf] = __builtin_amdgcn_mfma_f32_16x16x32_f16(aF[mf][sl], bF[nf][sl], acc[mf][nf], 0, 0, 0); \
        __builtin_amdgcn_s_setprio(0);                                        \
    }

    for (int tt = 0; tt < 6; ++tt) {
        GEMM_ITER(0)
        GEMM_ITER(1)
    }
#undef GEMM_ITER

    if (MODE == 0) {
        #pragma unroll
        for (int mf = 0; mf < 2; ++mf) {
            const int mblk = mblk0 + mf;
            #pragma unroll
            for (int r = 0; r < 4; ++r) {
                const int lane_r = lh * 4 + r;
                #pragma unroll
                for (int nf = 0; nf < 3; ++nf) {
                    const int c = bn + wc * 48 + nf * 16 + lr;
                    const int idx = (mblk * 24 + (c >> 5)) * 512
                                  + ((c >> 3) & 3) * 128 + lane_r * 8 + (c & 7);
                    Oh[idx] = f2h(fmaxf(acc[mf][nf][r], 0.f));
                }
            }
        }
        return;
    }

    // ---------------- MODE 1/2: phase 2 (adjacency GEMM) --------------------
    // drain: all waves done reading the K-loop buffers before hwT overwrites
    __builtin_amdgcn_s_barrier();
    __builtin_amdgcn_sched_barrier(0);

    // adj fragments straight to VGPRs (once per block)
    const u16* adjb = ADJ + (size_t)bmb * (N_ * N_);
    short8 adjr[8];
    #pragma unroll
    for (int mf = 0; mf < 2; ++mf)
        #pragma unroll
        for (int ks = 0; ks < 4; ++ks)
            adjr[mf * 4 + ks] = *(const short8*)(adjb +
                (size_t)(wr * 32 + mf * 16 + lr) * 128 + ks * 32 + lh * 8);

    // write H^T (single fp16) into LDS [c 96][node 128], chunk-swizzled
    u16* hwT = lds;
    #pragma unroll
    for (int mf = 0; mf < 2; ++mf) {
        const int node0 = wr * 32 + mf * 16 + lh * 4;
        #pragma unroll
        for (int nf = 0; nf < 3; ++nf) {
            const int c = wc * 48 + nf * 16 + lr;
            u16x4 hv;
            #pragma unroll
            for (int r = 0; r < 4; ++r) hv[r] = f2h(acc[mf][nf][r]);
            *(u16x4*)&hwT[c * 128 + (((node0 >> 3) ^ (c & 7)) << 3) + (node0 & 7)] = hv;
        }
    }
    asm volatile("s_waitcnt lgkmcnt(0)" ::: "memory");
    __builtin_amdgcn_s_barrier();
    __builtin_amdgcn_sched_barrier(0);

    f32x4 acc2[2][3];
    #pragma unroll
    for (int i = 0; i < 2; ++i)
        #pragma unroll
        for (int j = 0; j < 3; ++j)
            acc2[i][j] = (f32x4){0.f, 0.f, 0.f, 0.f};

    #pragma unroll
    for (int ks = 0; ks < 4; ++ks) {
        short8 bf[3];
        #pragma unroll
        for (int f = 0; f < 3; ++f) {
            const int c = wc * 48 + f * 16 + lr;
            bf[f] = *(const short8*)&hwT[c * 128 + (((ks * 4 + lh) ^ (c & 7)) << 3)];
        }
        #pragma unroll
        for (int mf = 0; mf < 2; ++mf)
            #pragma unroll
            for (int nf = 0; nf < 3; ++nf)
                acc2[mf][nf] = __builtin_amdgcn_mfma_f32_16x16x32_f16(adjr[mf * 4 + ks], bf[nf], acc2[mf][nf], 0, 0, 0);
    }

    // epilogue: v = relu(acc2*inv + bias) + X_in
    // MODE 1: store v (fp16) to Oh.   MODE 2: masked column sums -> GT.
    int gs = 0, ge = 0;
    if (MODE == 2) { gs = gspan[bmb * 2 + 0]; ge = gspan[bmb * 2 + 1]; }
    float pt[3] = {0.f, 0.f, 0.f};

    #pragma unroll
    for (int mf = 0; mf < 2; ++mf) {
        const int mblk = mblk0 + mf;
        #pragma unroll
        for (int r = 0; r < 4; ++r) {
            const int node = wr * 32 + mf * 16 + lh * 4 + r;
            const int lane_r = lh * 4 + r;
            const float inv = invden[bmb * N_ + node];
            const bool in_span = (node >= gs) && (node < ge);
            #pragma unroll
            for (int nf = 0; nf < 3; ++nf) {
                const int c = bn + wc * 48 + nf * 16 + lr;
                const int idx = (mblk * 24 + (c >> 5)) * 512
                              + ((c >> 3) & 3) * 128 + lane_r * 8 + (c & 7);
                float v = fmaxf(acc2[mf][nf][r] * inv + bias[c], 0.f);
                v += h2f(Ah[idx]);                  // residual = A-source
                const u16 hv = f2h(v);
                if (MODE == 1) Oh[idx] = hv;
                else if (in_span) pt[nf] += h2f(hv);
            }
        }
    }

    if (MODE == 2) {
        // deterministic block reduction: [96 cols][16 contributors] in LDS
        float* gtbuf = (float*)(lds + 16384);    // 6 KB, B region (dead)
        const int contrib = wr * 4 + lh;         // 0..15
        #pragma unroll
        for (int nf = 0; nf < 3; ++nf)
            gtbuf[(wc * 48 + nf * 16 + lr) * 16 + contrib] = pt[nf];
        asm volatile("s_waitcnt lgkmcnt(0)" ::: "memory");
        __builtin_amdgcn_s_barrier();
        __builtin_amdgcn_sched_barrier(0);
        if (tid < 96) {
            float s = 0.f;
            #pragma unroll
            for (int i = 0; i < 16; ++i) s += gtbuf[tid * 16 + i];
            GT[(size_t)bmb * D_ + bn + tid] = s;
        }
    }
}

// ---------------------------------------------------------------------------
// head: logits = tanh(concat(target_max, gcn_target) @ fcW + fcb).
// target_max computed on the fly from se (<=15 rows per batch).
__global__ __launch_bounds__(256)
void head_kernel(const float* __restrict__ se, const int* __restrict__ tspan,
                 const float* __restrict__ gt,
                 const float* __restrict__ fcW, const float* __restrict__ fcb,
                 float* __restrict__ out) {
    const int b = blockIdx.x;
    const int t = threadIdx.x;
    const int s = tspan[b * 2 + 0];
    const int e = tspan[b * 2 + 1];
    float p0 = 0.f, p1 = 0.f, p2 = 0.f;
    for (int i = t; i < 2 * D_; i += 256) {
        float v;
        if (i < D_) {
            const float* base = se + (size_t)b * S_ * D_ + i;
            float m = -FLT_MAX;
            for (int r = s; r < e; ++r) m = fmaxf(m, base[(size_t)r * D_]);
            v = m;
        } else {
            v = gt[(size_t)b * D_ + i - D_];
        }
        p0 += v * fcW[i * 3 + 0];
        p1 += v * fcW[i * 3 + 1];
        p2 += v * fcW[i * 3 + 2];
    }
    #pragma unroll
    for (int off = 32; off; off >>= 1) {
        p0 += __shfl_down(p0, off, 64);
        p1 += __shfl_down(p1, off, 64);
        p2 += __shfl_down(p2, off, 64);
    }
    __shared__ float red[4][3];
    const int wv = t >> 6;
    if ((t & 63) == 0) { red[wv][0] = p0; red[wv][1] = p1; red[wv][2] = p2; }
    __syncthreads();
    if (t == 0) {
        #pragma unroll
        for (int o = 0; o < 3; ++o) {
            const float sacc = red[0][o] + red[1][o] + red[2][o] + red[3][o] + fcb[o];
            out[b * 3 + o] = tanhf(sacc);
        }
    }
}

// ---------------------------------------------------------------------------
extern "C" void kernel_launch(void* const* d_in, const int* in_sizes, int n_in,
                              void* d_out, int out_size, void* d_ws, size_t ws_size,
                              hipStream_t stream) {
    const float* se   = (const float*)d_in[0];
    const float* dg   = (const float*)d_in[1];
    const float* dg1  = (const float*)d_in[2];
    const float* Wp   = (const float*)d_in[3];
    const float* Wg1  = (const float*)d_in[4];
    const float* bg0p = (const float*)d_in[5];
    const float* Wg2  = (const float*)d_in[6];
    const float* bg1p = (const float*)d_in[7];
    const float* Wg3  = (const float*)d_in[8];
    const float* bg2p = (const float*)d_in[9];
    const float* fcW  = (const float*)d_in[10];
    const float* fcb  = (const float*)d_in[11];
    const int*   tspan  = (const int*)d_in[12];
    const int*   nspans = (const int*)d_in[13];
    const int*   gspan  = (const int*)d_in[14];
    float* out = (float*)d_out;

    // workspace layout (u16 units unless noted)
    u16* us   = (u16*)d_ws;
    u16* X0   = us;                        // 8192*768 (FRAG layout, fp16)
    u16* X1   = X0 + 6291456;
    u16* TH   = X1 + 6291456;              // tmps (FRAG layout, fp16)
    u16* WTh  = TH + 6291456;              // 4*768*768 fp16
    u16* ADJ  = WTh + 2359296;             // 64*128*128 fp16
    float* INV = (float*)(ADJ + 1048576);  // 8192
    float* GT  = INV + 8192;               // 64*768

    // Stage A: ragged prep (span-sum + adjacency merged) + weight transpose
    prep_kernel<<<16384, 192, 0, stream>>>(se, nspans, TH, dg, dg1, ADJ, INV);
    wsplit_kernel<<<dim3(12, 12, 4), 256, 0, stream>>>(Wp, Wg1, Wg2, Wg3, WTh);

    // Stage B: X0 = relu(tmps @ W_proj)
    gemm_fused<0><<<512, 512, 0, stream>>>(TH, WTh, nullptr, nullptr, nullptr,
                                           X0, nullptr, nullptr);

    // Stage C: GCN layers 1,2 (ping-pong), layer 3 fused with gcn_target
    gemm_fused<1><<<512, 512, 0, stream>>>(X0, WTh + (size_t)1 * D_ * D_,
                                           ADJ, INV, bg0p, X1, nullptr, nullptr);
    gemm_fused<1><<<512, 512, 0, stream>>>(X1, WTh + (size_t)2 * D_ * D_,
                                           ADJ, INV, bg1p, X0, nullptr, nullptr);
    gemm_fused<2><<<512, 512, 0, stream>>>(X0, WTh + (size_t)3 * D_ * D_,
                                           ADJ, INV, bg2p, X1, gspan, GT);

    // Stage D: head (target_max computed inline)
    head_kernel<<<B_, 256, 0, stream>>>(se, tspan, GT, fcW, fcb, out);
}

// Round 19
// 101.942 us; speedup vs baseline: 1.3890x; 1.0158x over previous
//
#include <hip/hip_runtime.h>
#include <float.h>
#include <math.h>

typedef __attribute__((ext_vector_type(8))) short short8;
typedef __attribute__((ext_vector_type(4))) float f32x4;
typedef __attribute__((ext_vector_type(4))) unsigned short u16x4;
typedef unsigned short u16;
typedef unsigned int u32;

constexpr int B_ = 64, S_ = 512, N_ = 128, D_ = 768;

// ---------------------------------------------------------------------------
__device__ inline u16 f2h(float x) {
    _Float16 hh = (_Float16)x;
    return __builtin_bit_cast(u16, hh);
}
__device__ inline float h2f(u16 h) {
    return (float)__builtin_bit_cast(_Float16, h);
}

__device__ inline void gload_lds16(const u16* g, u16* s) {
    __builtin_amdgcn_global_load_lds(
        (const __attribute__((address_space(1))) u32*)g,
        (__attribute__((address_space(3))) u32*)s, 16, 0, 0);
}

// Fragment-major layout for activation matrices [M][768]:
// u16 index of (row, col) = ((row>>4)*24 + (col>>5))*512
//                         + ((col>>3)&3)*128 + (row&15)*8 + (col&7)
__device__ inline int fragIdx(int row, int col) {
    return ((row >> 4) * 24 + (col >> 5)) * 512 + ((col >> 3) & 3) * 128
         + (row & 15) * 8 + (col & 7);
}

// ---------------------------------------------------------------------------
// prep: blocks [0,8192)      = span-sum -> TH (FRAG fp16)
//       blocks [8192,16384)  = adj row -> ADJ fp16 + invden
//       blocks [16384,16960) = weight transpose tile -> WTh fp16
__global__ __launch_bounds__(256)
void prep_kernel(const float* __restrict__ se, const int* __restrict__ spans,
                 u16* __restrict__ th,
                 const float* __restrict__ dg, const float* __restrict__ dg1,
                 u16* __restrict__ adj, float* __restrict__ invden,
                 const float* __restrict__ W0, const float* __restrict__ W1,
                 const float* __restrict__ W2, const float* __restrict__ W3,
                 u16* __restrict__ wth) {
    __shared__ float t[64][65];          // wsplit tile; ssum aliases t[0][0..1]
    const int bid = blockIdx.x;
    const int tid = threadIdx.x;
    if (bid < 8192) {
        if (tid >= 192) return;
        const int bn = bid;
        const int b  = bn >> 7;
        const int s  = spans[bn * 2 + 0];
        const int e  = spans[bn * 2 + 1];
        const float* base = se + (size_t)b * S_ * D_;
        float4 acc = make_float4(0.f, 0.f, 0.f, 0.f);
        for (int r = s + 1; r <= e; ++r) {
            const float4 v = reinterpret_cast<const float4*>(base + (size_t)r * D_)[tid];
            acc.x += v.x; acc.y += v.y; acc.z += v.z; acc.w += v.w;
        }
        u16x4 hv;
        hv[0] = f2h(acc.x); hv[1] = f2h(acc.y);
        hv[2] = f2h(acc.z); hv[3] = f2h(acc.w);
        *(u16x4*)(th + fragIdx(bn, tid * 4)) = hv;
    } else if (bid < 16384) {
        const int row = bid - 8192;
        if (tid < 128) {
            const size_t idx = (size_t)row * N_ + tid;
            float a = dg[idx] + dg1[idx];
            a = (a >= 1.f) ? 1.f : a;
            adj[idx] = f2h(a);
            float w = a;
            #pragma unroll
            for (int off = 32; off; off >>= 1) w += __shfl_down(w, off, 64);
            if ((tid & 63) == 0) t[0][tid >> 6] = w;
        }
        __syncthreads();
        if (tid == 0) invden[row] = 1.f / (t[0][0] + t[0][1] + 1e-7f);
    } else {
        const int widx = bid - 16384;            // 576 tiles: mi*144 + ky*12 + nx
        const int mi  = widx / 144;
        const int rem = widx - mi * 144;
        const int k0 = (rem / 12) * 64, n0 = (rem % 12) * 64;
        const float* W = (mi == 0) ? W0 : (mi == 1) ? W1 : (mi == 2) ? W2 : W3;
        #pragma unroll 4
        for (int it = 0; it < 16; ++it) {
            const int lin = it * 256 + tid;
            const int r = lin >> 6, c = lin & 63;
            t[r][c] = W[(size_t)(k0 + r) * D_ + n0 + c];
        }
        __syncthreads();
        u16* oh = wth + (size_t)mi * D_ * D_;
        #pragma unroll 4
        for (int it = 0; it < 16; ++it) {
            const int lin = it * 256 + tid;
            const int r = lin >> 6, c = lin & 63;
            oh[(size_t)(n0 + r) * D_ + k0 + c] = f2h(t[c][r]);
        }
    }
}

// ---------------------------------------------------------------------------
// Fused fp16 GEMM (H ~= A @ W, all single fp16 storage).
// 128x96 tile, BK=64 (12 K-iterations), 8 waves (4x2), 512 blocks (2/CU).
// LDS 56 KB: A dbuf 2x16KB [0,16384) u16 | B dbuf 2x12KB [16384,28672) u16.
// Single barrier per K-step; stage-after-barrier into buf (t+1)&1.
// MODE 0: store relu(H) single fp16, FRAG layout.
// MODE 1: out = relu((adj[b]@H)*invden + bias) + X_in (FRAG layout).
// MODE 2: as MODE 1, but final layer: do NOT store X; instead compute the
//   gcn_span-masked node-sum per column in-register, reduce via LDS
//   [96][16] (deterministic fixed-order), write GT[b][bn..bn+95].
template<int MODE>
__global__ __launch_bounds__(512, 4)
void gemm_fused(const u16* __restrict__ Ah,
                const u16* __restrict__ Bh,
                const u16* __restrict__ ADJ, const float* __restrict__ invden,
                const float* __restrict__ bias,
                u16* __restrict__ Oh,
                const int* __restrict__ gspan, float* __restrict__ GT) {
    __shared__ u16 lds[28672];   // A dbuf [0,16384) | B dbuf [16384,28672)
    const int tid  = threadIdx.x;
    const int lane = tid & 63, w = tid >> 6;     // 8 waves
    const int wr = w >> 1, wc = w & 1;           // 4 row x 2 col
    const int lr = lane & 15, lh = lane >> 4;

    int bid = blockIdx.x;
    bid = (bid & 7) * 64 + (bid >> 3);           // XCD swizzle (512 % 8 == 0)
    const int bnb = bid & 7, bmb = bid >> 3;
    const int bn = bnb * 96;

    // --- B staging: wave w<6 stages rows w*16..w*16+15, both 32-k slices ---
    const int qch = (lane & 3) ^ ((lane >> 3) & 3);
    const u16* gBsrc = Bh + (size_t)(bn + w * 16 + (lane >> 2)) * 768 + qch * 8;

    // --- A staging: wave w stages mblk (bmb*8 + w), both slices (1KB each) ---
    const int mblk0 = bmb * 8 + wr * 2;          // wave's compute mblks
    const u16* gAstage = Ah + (size_t)(bmb * 8 + w) * 12288 + lane * 8;

    f32x4 acc[2][3];
    #pragma unroll
    for (int i = 0; i < 2; ++i)
        #pragma unroll
        for (int j = 0; j < 3; ++j)
            acc[i][j] = (f32x4){0.f, 0.f, 0.f, 0.f};

    // prologue: stage K-tile 0 into buf0 (A: 2 slices; B: 2 slices for w<6)
    gload_lds16(gAstage,       lds + w * 1024);
    gload_lds16(gAstage + 512, lds + w * 1024 + 512);
    if (w < 6) {
        gload_lds16(gBsrc,      lds + 16384 + w * 512);
        gload_lds16(gBsrc + 32, lds + 16384 + 3072 + w * 512);
    }

    const int pB = (lh ^ ((lr >> 1) & 3)) << 3;  // B frag phys chunk offset (u16)

// One K-step (64 wide). C = compile-time phase (t_ & 1).
#define GEMM_ITER(C)                                                          \
    {                                                                         \
        const int t_ = 2 * tt + (C);                                          \
        asm volatile("s_waitcnt vmcnt(0)" ::: "memory");                      \
        __builtin_amdgcn_s_barrier();                                         \
        __builtin_amdgcn_sched_barrier(0);                                    \
        if (t_ <= 10) {                                                       \
            u16* ab = lds + (((C) + 1) & 1) * 8192;                           \
            gload_lds16(gAstage + (2 * (t_ + 1)) * 512,     ab + w * 1024);   \
            gload_lds16(gAstage + (2 * (t_ + 1) + 1) * 512, ab + w * 1024 + 512); \
            if (w < 6) {                                                      \
                u16* bb = lds + 16384 + (((C) + 1) & 1) * 6144;               \
                gload_lds16(gBsrc + (t_ + 1) * 64,      bb + w * 512);        \
                gload_lds16(gBsrc + (t_ + 1) * 64 + 32, bb + 3072 + w * 512); \
            }                                                                 \
        }                                                                     \
        const u16* La = lds + ((C) & 1) * 8192;                               \
        const u16* Lb = lds + 16384 + ((C) & 1) * 6144;                       \
        short8 aF[2][2], bF[3][2];                                            \
        _Pragma("unroll")                                                     \
        for (int sl = 0; sl < 2; ++sl) {                                      \
            aF[0][sl] = *(const short8*)&La[(wr * 2) * 1024 + sl * 512 + lane * 8];     \
            aF[1][sl] = *(const short8*)&La[(wr * 2 + 1) * 1024 + sl * 512 + lane * 8]; \
            _Pragma("unroll")                                                 \
            for (int f = 0; f < 3; ++f)                                       \
                bF[f][sl] = *(const short8*)&Lb[sl * 3072 + (wc * 48 + f * 16 + lr) * 32 + pB]; \
        }                                                                     \
        __builtin_amdgcn_s_setprio(1);                                        \
        _Pragma("unroll")                                                     \
        for (int sl = 0; sl < 2; ++sl)                                        \
            _Pragma("unroll")                                                 \
            for (int mf = 0; mf < 2; ++mf)                                    \
                _Pragma("unroll")                                             \
                for (int nf = 0; nf < 3; ++nf)                                \
                    acc[mf][nf] = __builtin_amdgcn_mfma_f32_16x16x32_f16(aF[mf][sl], bF[nf][sl], acc[mf][nf], 0, 0, 0); \
        __builtin_amdgcn_s_setprio(0);                                        \
    }

    for (int tt = 0; tt < 6; ++tt) {
        GEMM_ITER(0)
        GEMM_ITER(1)
    }
#undef GEMM_ITER

    if (MODE == 0) {
        #pragma unroll
        for (int mf = 0; mf < 2; ++mf) {
            const int mblk = mblk0 + mf;
            #pragma unroll
            for (int r = 0; r < 4; ++r) {
                const int lane_r = lh * 4 + r;
                #pragma unroll
                for (int nf = 0; nf < 3; ++nf) {
                    const int c = bn + wc * 48 + nf * 16 + lr;
                    const int idx = (mblk * 24 + (c >> 5)) * 512
                                  + ((c >> 3) & 3) * 128 + lane_r * 8 + (c & 7);
                    Oh[idx] = f2h(fmaxf(acc[mf][nf][r], 0.f));
                }
            }
        }
        return;
    }

    // ---------------- MODE 1/2: phase 2 (adjacency GEMM) --------------------
    // drain: all waves done reading the K-loop buffers before hwT overwrites
    __builtin_amdgcn_s_barrier();
    __builtin_amdgcn_sched_barrier(0);

    // adj fragments straight to VGPRs (once per block)
    const u16* adjb = ADJ + (size_t)bmb * (N_ * N_);
    short8 adjr[8];
    #pragma unroll
    for (int mf = 0; mf < 2; ++mf)
        #pragma unroll
        for (int ks = 0; ks < 4; ++ks)
            adjr[mf * 4 + ks] = *(const short8*)(adjb +
                (size_t)(wr * 32 + mf * 16 + lr) * 128 + ks * 32 + lh * 8);

    // write H^T (single fp16) into LDS [c 96][node 128], chunk-swizzled
    u16* hwT = lds;
    #pragma unroll
    for (int mf = 0; mf < 2; ++mf) {
        const int node0 = wr * 32 + mf * 16 + lh * 4;
        #pragma unroll
        for (int nf = 0; nf < 3; ++nf) {
            const int c = wc * 48 + nf * 16 + lr;
            u16x4 hv;
            #pragma unroll
            for (int r = 0; r < 4; ++r) hv[r] = f2h(acc[mf][nf][r]);
            *(u16x4*)&hwT[c * 128 + (((node0 >> 3) ^ (c & 7)) << 3) + (node0 & 7)] = hv;
        }
    }
    asm volatile("s_waitcnt lgkmcnt(0)" ::: "memory");
    __builtin_amdgcn_s_barrier();
    __builtin_amdgcn_sched_barrier(0);

    f32x4 acc2[2][3];
    #pragma unroll
    for (int i = 0; i < 2; ++i)
        #pragma unroll
        for (int j = 0; j < 3; ++j)
            acc2[i][j] = (f32x4){0.f, 0.f, 0.f, 0.f};

    #pragma unroll
    for (int ks = 0; ks < 4; ++ks) {
        short8 bf[3];
        #pragma unroll
        for (int f = 0; f < 3; ++f) {
            const int c = wc * 48 + f * 16 + lr;
            bf[f] = *(const short8*)&hwT[c * 128 + (((ks * 4 + lh) ^ (c & 7)) << 3)];
        }
        #pragma unroll
        for (int mf = 0; mf < 2; ++mf)
            #pragma unroll
            for (int nf = 0; nf < 3; ++nf)
                acc2[mf][nf] = __builtin_amdgcn_mfma_f32_16x16x32_f16(adjr[mf * 4 + ks], bf[nf], acc2[mf][nf], 0, 0, 0);
    }

    // epilogue: v = relu(acc2*inv + bias) + X_in
    // MODE 1: store v (fp16) to Oh.   MODE 2: masked column sums -> GT.
    int gs = 0, ge = 0;
    if (MODE == 2) { gs = gspan[bmb * 2 + 0]; ge = gspan[bmb * 2 + 1]; }
    float pt[3] = {0.f, 0.f, 0.f};

    #pragma unroll
    for (int mf = 0; mf < 2; ++mf) {
        const int mblk = mblk0 + mf;
        #pragma unroll
        for (int r = 0; r < 4; ++r) {
            const int node = wr * 32 + mf * 16 + lh * 4 + r;
            const int lane_r = lh * 4 + r;
            const float inv = invden[bmb * N_ + node];
            const bool in_span = (node >= gs) && (node < ge);
            #pragma unroll
            for (int nf = 0; nf < 3; ++nf) {
                const int c = bn + wc * 48 + nf * 16 + lr;
                const int idx = (mblk * 24 + (c >> 5)) * 512
                              + ((c >> 3) & 3) * 128 + lane_r * 8 + (c & 7);
                float v = fmaxf(acc2[mf][nf][r] * inv + bias[c], 0.f);
                v += h2f(Ah[idx]);                  // residual = A-source
                const u16 hv = f2h(v);
                if (MODE == 1) Oh[idx] = hv;
                else if (in_span) pt[nf] += h2f(hv);
            }
        }
    }

    if (MODE == 2) {
        // deterministic block reduction: [96 cols][16 contributors] in LDS
        float* gtbuf = (float*)(lds + 16384);    // 6 KB, B region (dead)
        const int contrib = wr * 4 + lh;         // 0..15
        #pragma unroll
        for (int nf = 0; nf < 3; ++nf)
            gtbuf[(wc * 48 + nf * 16 + lr) * 16 + contrib] = pt[nf];
        asm volatile("s_waitcnt lgkmcnt(0)" ::: "memory");
        __builtin_amdgcn_s_barrier();
        __builtin_amdgcn_sched_barrier(0);
        if (tid < 96) {
            float s = 0.f;
            #pragma unroll
            for (int i = 0; i < 16; ++i) s += gtbuf[tid * 16 + i];
            GT[(size_t)bmb * D_ + bn + tid] = s;
        }
    }
}

// ---------------------------------------------------------------------------
// head: logits = tanh(concat(target_max, gcn_target) @ fcW + fcb).
// target_max computed on the fly from se (<=15 rows per batch).
__global__ __launch_bounds__(256)
void head_kernel(const float* __restrict__ se, const int* __restrict__ tspan,
                 const float* __restrict__ gt,
                 const float* __restrict__ fcW, const float* __restrict__ fcb,
                 float* __restrict__ out) {
    const int b = blockIdx.x;
    const int t = threadIdx.x;
    const int s = tspan[b * 2 + 0];
    const int e = tspan[b * 2 + 1];
    float p0 = 0.f, p1 = 0.f, p2 = 0.f;
    for (int i = t; i < 2 * D_; i += 256) {
        float v;
        if (i < D_) {
            const float* base = se + (size_t)b * S_ * D_ + i;
            float m = -FLT_MAX;
            for (int r = s; r < e; ++r) m = fmaxf(m, base[(size_t)r * D_]);
            v = m;
        } else {
            v = gt[(size_t)b * D_ + i - D_];
        }
        p0 += v * fcW[i * 3 + 0];
        p1 += v * fcW[i * 3 + 1];
        p2 += v * fcW[i * 3 + 2];
    }
    #pragma unroll
    for (int off = 32; off; off >>= 1) {
        p0 += __shfl_down(p0, off, 64);
        p1 += __shfl_down(p1, off, 64);
        p2 += __shfl_down(p2, off, 64);
    }
    __shared__ float red[4][3];
    const int wv = t >> 6;
    if ((t & 63) == 0) { red[wv][0] = p0; red[wv][1] = p1; red[wv][2] = p2; }
    __syncthreads();
    if (t == 0) {
        #pragma unroll
        for (int o = 0; o < 3; ++o) {
            const float sacc = red[0][o] + red[1][o] + red[2][o] + red[3][o] + fcb[o];
            out[b * 3 + o] = tanhf(sacc);
        }
    }
}

// ---------------------------------------------------------------------------
extern "C" void kernel_launch(void* const* d_in, const int* in_sizes, int n_in,
                              void* d_out, int out_size, void* d_ws, size_t ws_size,
                              hipStream_t stream) {
    const float* se   = (const float*)d_in[0];
    const float* dg   = (const float*)d_in[1];
    const float* dg1  = (const float*)d_in[2];
    const float* Wp   = (const float*)d_in[3];
    const float* Wg1  = (const float*)d_in[4];
    const float* bg0p = (const float*)d_in[5];
    const float* Wg2  = (const float*)d_in[6];
    const float* bg1p = (const float*)d_in[7];
    const float* Wg3  = (const float*)d_in[8];
    const float* bg2p = (const float*)d_in[9];
    const float* fcW  = (const float*)d_in[10];
    const float* fcb  = (const float*)d_in[11];
    const int*   tspan  = (const int*)d_in[12];
    const int*   nspans = (const int*)d_in[13];
    const int*   gspan  = (const int*)d_in[14];
    float* out = (float*)d_out;

    // workspace layout (u16 units unless noted)
    u16* us   = (u16*)d_ws;
    u16* X0   = us;                        // 8192*768 (FRAG layout, fp16)
    u16* X1   = X0 + 6291456;
    u16* TH   = X1 + 6291456;              // tmps (FRAG layout, fp16)
    u16* WTh  = TH + 6291456;              // 4*768*768 fp16
    u16* ADJ  = WTh + 2359296;             // 64*128*128 fp16
    float* INV = (float*)(ADJ + 1048576);  // 8192
    float* GT  = INV + 8192;               // 64*768

    // Stage A: all prep in ONE launch (span-sum + adjacency + W transpose)
    prep_kernel<<<16960, 256, 0, stream>>>(se, nspans, TH, dg, dg1, ADJ, INV,
                                           Wp, Wg1, Wg2, Wg3, WTh);

    // Stage B: X0 = relu(tmps @ W_proj)
    gemm_fused<0><<<512, 512, 0, stream>>>(TH, WTh, nullptr, nullptr, nullptr,
                                           X0, nullptr, nullptr);

    // Stage C: GCN layers 1,2 (ping-pong), layer 3 fused with gcn_target
    gemm_fused<1><<<512, 512, 0, stream>>>(X0, WTh + (size_t)1 * D_ * D_,
                                           ADJ, INV, bg0p, X1, nullptr, nullptr);
    gemm_fused<1><<<512, 512, 0, stream>>>(X1, WTh + (size_t)2 * D_ * D_,
                                           ADJ, INV, bg1p, X0, nullptr, nullptr);
    gemm_fused<2><<<512, 512, 0, stream>>>(X0, WTh + (size_t)3 * D_ * D_,
                                           ADJ, INV, bg2p, X1, gspan, GT);

    // Stage D: head (target_max computed inline)
    head_kernel<<<B_, 256, 0, stream>>>(se, tspan, GT, fcW, fcb, out);
}